// Round 2
// baseline (1546.421 us; speedup 1.0000x reference)
//
#include <hip/hip_runtime.h>
#include <math.h>

#define N_NODES 50000
#define N_EDGES 800000
#define NB      64
#define ND      64
#define ED      16
#define HID     128
#define NC      6
#define POOL_SPLIT 16

__device__ __forceinline__ float wave_sum(float v) {
    #pragma unroll
    for (int o = 32; o > 0; o >>= 1) v += __shfl_xor(v, o, 64);
    return v;
}

// ---------------- h0 = relu(x @ pW + pb) ----------------
__global__ void k_proj(const float* __restrict__ x, const float* __restrict__ pW,
                       const float* __restrict__ pb, float* __restrict__ h) {
    int n = blockIdx.x;
    int c = threadIdx.x;               // 128 threads
    __shared__ float xs[ND];
    if (c < ND) xs[c] = x[(size_t)n * ND + c];
    __syncthreads();
    float acc = pb[c];
    #pragma unroll 8
    for (int k = 0; k < ND; k++) acc += xs[k] * pW[k * HID + c];
    h[(size_t)n * HID + c] = fmaxf(acc, 0.f);
}

// ---------------- CSR build ----------------
__global__ void k_deg(const int* __restrict__ dst, int* __restrict__ deg) {
    int e = blockIdx.x * blockDim.x + threadIdx.x;
    if (e < N_EDGES) atomicAdd(&deg[dst[e]], 1);
}

__global__ void k_scan(const int* __restrict__ deg, int* __restrict__ offs) {
    __shared__ int sums[1024];
    int t = threadIdx.x;
    const int CH = (N_NODES + 1023) / 1024;  // 49
    int start = t * CH, end = min(start + CH, N_NODES);
    int s = 0;
    for (int i = start; i < end; i++) s += deg[i];
    sums[t] = s;
    __syncthreads();
    for (int o = 1; o < 1024; o <<= 1) {
        int v = (t >= o) ? sums[t - o] : 0;
        __syncthreads();
        sums[t] += v;
        __syncthreads();
    }
    int run = (t == 0) ? 0 : sums[t - 1];
    for (int i = start; i < end; i++) { offs[i] = run; run += deg[i]; }
    if (t == 1023) offs[N_NODES] = sums[1023];
}

__global__ void k_pos(const int* __restrict__ offs, int* __restrict__ pos) {
    int n = blockIdx.x * blockDim.x + threadIdx.x;
    if (n < N_NODES) pos[n] = offs[n];
}

__global__ void k_scatter(const int* __restrict__ dst, int* __restrict__ pos,
                          int* __restrict__ eidx) {
    int e = blockIdx.x * blockDim.x + threadIdx.x;
    if (e < N_EDGES) {
        int p = atomicAdd(&pos[dst[e]], 1);
        eidx[p] = e;
    }
}

// ---------------- per-layer: xp = h@W, al_src/al_dst ----------------
template <int H>
__global__ void k_node_proj(const float* __restrict__ h, const float* __restrict__ W,
                            const float* __restrict__ as_, const float* __restrict__ ad_,
                            float* __restrict__ xp, float* __restrict__ al_src,
                            float* __restrict__ al_dst) {
    const int C = HID / H;
    int n = blockIdx.x;
    int c = threadIdx.x;               // 128 threads
    __shared__ float hs[HID];
    __shared__ float rs[HID];
    __shared__ float rd[HID];
    hs[c] = h[(size_t)n * HID + c];
    __syncthreads();
    float acc = 0.f;
    #pragma unroll 8
    for (int k = 0; k < HID; k++) acc += hs[k] * W[k * HID + c];
    xp[(size_t)n * HID + c] = acc;
    rs[c] = acc * as_[c];
    rd[c] = acc * ad_[c];
    __syncthreads();
    for (int s = C / 2; s > 0; s >>= 1) {
        if ((c & (C - 1)) < s) { rs[c] += rs[c + s]; rd[c] += rd[c + s]; }
        __syncthreads();
    }
    if ((c & (C - 1)) == 0) {
        al_src[n * H + c / C] = rs[c];
        al_dst[n * H + c / C] = rd[c];
    }
}

// ---------------- WeAe[k][h] = sum_c We[k, h*C+c] * ae[h,c]  (16 x H) ----------------
template <int H>
__global__ void k_weae(const float* __restrict__ We, const float* __restrict__ ae,
                       float* __restrict__ WeAe) {
    const int C = HID / H;
    int t = threadIdx.x;
    if (t < ED * H) {
        int k = t / H, hh = t % H;
        float s = 0.f;
        for (int cc = 0; cc < C; cc++)
            s += We[k * HID + hh * C + cc] * ae[hh * C + cc];
        WeAe[k * H + hh] = s;
    }
}

// ---------------- al_edge = ea @ WeAe  [E,H] ----------------
template <int H>
__global__ void k_edge_al(const float* __restrict__ ea, const float* __restrict__ WeAe,
                          float* __restrict__ al_edge) {
    __shared__ float w[ED * 4];
    int tid = threadIdx.x;
    if (tid < ED * H) w[tid] = WeAe[tid];
    __syncthreads();
    int e = blockIdx.x * blockDim.x + tid;
    if (e >= N_EDGES) return;
    float ev[ED];
    const float4* ep4 = reinterpret_cast<const float4*>(ea + (size_t)e * ED);
    #pragma unroll
    for (int q = 0; q < 4; q++) {
        float4 v = ep4[q];
        ev[q * 4 + 0] = v.x; ev[q * 4 + 1] = v.y;
        ev[q * 4 + 2] = v.z; ev[q * 4 + 3] = v.w;
    }
    #pragma unroll
    for (int hh = 0; hh < H; hh++) {
        float s = 0.f;
        #pragma unroll
        for (int k = 0; k < ED; k++) s += ev[k] * w[k * H + hh];
        al_edge[(size_t)e * H + hh] = s;
    }
}

// ---------------- fused: segment softmax + aggregate + bias + LN + ELU + residual ----------------
// one wave (64 lanes) per destination node; lane handles channels lane and lane+64
template <int H>
__global__ void k_node_agg(const int* __restrict__ src, const int* __restrict__ offs,
                           const int* __restrict__ eidx, const float* __restrict__ xp,
                           const float* __restrict__ al_src, const float* __restrict__ al_dst,
                           const float* __restrict__ al_edge, const float* __restrict__ bias,
                           const float* __restrict__ g, const float* __restrict__ be,
                           const float* __restrict__ hin, float* __restrict__ hout) {
    const int C = HID / H;
    int wave = threadIdx.x >> 6;
    int lane = threadIdx.x & 63;
    int n = blockIdx.x * 4 + wave;
    if (n >= N_NODES) return;
    int e0 = offs[n], e1 = offs[n + 1];
    float ald[H];
    #pragma unroll
    for (int hh = 0; hh < H; hh++) ald[hh] = al_dst[n * H + hh];
    // pass 1: per-head max of leaky_relu(alpha)
    float m[H];
    #pragma unroll
    for (int hh = 0; hh < H; hh++) m[hh] = -__builtin_inff();
    for (int i = e0; i < e1; i++) {
        int e = eidx[i];
        int s = src[e];
        #pragma unroll
        for (int hh = 0; hh < H; hh++) {
            float a = al_src[s * H + hh] + ald[hh] + al_edge[(size_t)e * H + hh];
            a = (a >= 0.f) ? a : 0.2f * a;
            m[hh] = fmaxf(m[hh], a);
        }
    }
    // pass 2: weighted gather
    float den[H];
    #pragma unroll
    for (int hh = 0; hh < H; hh++) den[hh] = 0.f;
    float acc0 = 0.f, acc1 = 0.f;
    const int c0 = lane, c1 = lane + 64;
    const int h0 = c0 / C, h1 = c1 / C;
    for (int i = e0; i < e1; i++) {
        int e = eidx[i];
        int s = src[e];
        float w[H];
        #pragma unroll
        for (int hh = 0; hh < H; hh++) {
            float a = al_src[s * H + hh] + ald[hh] + al_edge[(size_t)e * H + hh];
            a = (a >= 0.f) ? a : 0.2f * a;
            w[hh] = __expf(a - m[hh]);
            den[hh] += w[hh];
        }
        acc0 += w[h0] * xp[(size_t)s * HID + c0];
        acc1 += w[h1] * xp[(size_t)s * HID + c1];
    }
    float v0 = acc0 / (den[h0] + 1e-16f) + bias[c0];
    float v1 = acc1 / (den[h1] + 1e-16f) + bias[c1];
    // layernorm over the 128 channels held by this wave
    float mean = wave_sum(v0 + v1) * (1.f / HID);
    float d0 = v0 - mean, d1 = v1 - mean;
    float var = wave_sum(d0 * d0 + d1 * d1) * (1.f / HID);
    float rstd = rsqrtf(var + 1e-5f);
    float y0 = d0 * rstd * g[c0] + be[c0];
    float y1 = d1 * rstd * g[c1] + be[c1];
    y0 = (y0 > 0.f) ? y0 : (__expf(y0) - 1.f);
    y1 = (y1 > 0.f) ? y1 : (__expf(y1) - 1.f);
    hout[(size_t)n * HID + c0] = y0 + hin[(size_t)n * HID + c0];
    hout[(size_t)n * HID + c1] = y1 + hin[(size_t)n * HID + c1];
}

// ---------------- gate[n] = relu(h@gW1+gb1)@gW2 + gb2 ----------------
__global__ void k_gate(const float* __restrict__ h, const float* __restrict__ gW1,
                       const float* __restrict__ gb1, const float* __restrict__ gW2,
                       const float* __restrict__ gb2, float* __restrict__ gate) {
    int n = blockIdx.x;
    int t = threadIdx.x;               // 64 threads
    __shared__ float hr[HID];
    hr[t] = h[(size_t)n * HID + t];
    hr[t + 64] = h[(size_t)n * HID + t + 64];
    __syncthreads();
    float a = gb1[t];
    #pragma unroll 8
    for (int k = 0; k < HID; k++) a += hr[k] * gW1[k * 64 + t];
    a = fmaxf(a, 0.f);
    float p = wave_sum(a * gW2[t]);
    if (t == 0) gate[n] = p + gb2[0];
}

// ---------------- graph boundaries from sorted batch ----------------
__global__ void k_bounds(const int* __restrict__ batch, int* __restrict__ goff) {
    int n = blockIdx.x * blockDim.x + threadIdx.x;
    if (n >= N_NODES) return;
    int cur = batch[n];
    int prev = (n == 0) ? -1 : batch[n - 1];
    for (int g = prev + 1; g <= cur; g++) goff[g] = n;
    if (n == N_NODES - 1) {
        for (int g = cur + 1; g <= NB; g++) goff[g] = N_NODES;
    }
}

__global__ void k_gmaxden(const float* __restrict__ gate, const int* __restrict__ goff,
                          float* __restrict__ gmax, float* __restrict__ gden) {
    int b = blockIdx.x;
    int t = threadIdx.x;               // 256 threads
    __shared__ float red[256];
    int s = goff[b], e = goff[b + 1];
    float m = -__builtin_inff();
    for (int n = s + t; n < e; n += 256) m = fmaxf(m, gate[n]);
    red[t] = m;
    __syncthreads();
    for (int o = 128; o > 0; o >>= 1) { if (t < o) red[t] = fmaxf(red[t], red[t + o]); __syncthreads(); }
    m = red[0];
    __syncthreads();
    float d = 0.f;
    for (int n = s + t; n < e; n += 256) d += __expf(gate[n] - m);
    red[t] = d;
    __syncthreads();
    for (int o = 128; o > 0; o >>= 1) { if (t < o) red[t] += red[t + o]; __syncthreads(); }
    if (t == 0) { gmax[b] = m; gden[b] = red[0]; }
}

__global__ void k_watt(const float* __restrict__ gate, const int* __restrict__ batch,
                       const float* __restrict__ gmax, const float* __restrict__ gden,
                       float* __restrict__ watt) {
    int n = blockIdx.x * blockDim.x + threadIdx.x;
    if (n >= N_NODES) return;
    int b = batch[n];
    watt[n] = __expf(gate[n] - gmax[b]) / (gden[b] + 1e-16f);
}

__global__ void k_pool(const float* __restrict__ h, const float* __restrict__ watt,
                       const int* __restrict__ goff, float* __restrict__ pooled) {
    int b = blockIdx.x;
    int part = blockIdx.y;
    int c = threadIdx.x;               // 128 threads
    int s = goff[b], e = goff[b + 1];
    float acc = 0.f;
    for (int n = s + part; n < e; n += POOL_SPLIT)
        acc += watt[n] * h[(size_t)n * HID + c];
    atomicAdd(&pooled[b * HID + c], acc);
}

__global__ void k_head(const float* __restrict__ pooled, const float* __restrict__ cW1,
                       const float* __restrict__ cb1, const float* __restrict__ cW2,
                       const float* __restrict__ cb2, float* __restrict__ out) {
    int b = blockIdx.x;
    int t = threadIdx.x;               // 64 threads
    __shared__ float pr[HID];
    __shared__ float tr[64];
    pr[t] = pooled[b * HID + t];
    pr[t + 64] = pooled[b * HID + t + 64];
    __syncthreads();
    float a = cb1[t];
    #pragma unroll 8
    for (int k = 0; k < HID; k++) a += pr[k] * cW1[k * 64 + t];
    tr[t] = fmaxf(a, 0.f);
    __syncthreads();
    if (t < NC) {
        float o = cb2[t];
        #pragma unroll
        for (int k = 0; k < 64; k++) o += tr[k] * cW2[k * NC + t];
        out[b * NC + t] = o;
    }
}

extern "C" void kernel_launch(void* const* d_in, const int* in_sizes, int n_in,
                              void* d_out, int out_size, void* d_ws, size_t ws_size,
                              hipStream_t stream) {
    (void)in_sizes; (void)n_in; (void)out_size; (void)ws_size;
    const float* x     = (const float*)d_in[0];
    const int*   ei    = (const int*)d_in[1];
    const float* ea    = (const float*)d_in[2];
    const int*   batch = (const int*)d_in[3];
    const float* pW    = (const float*)d_in[4];
    const float* pb    = (const float*)d_in[5];
    const float *W[3], *as_[3], *ad_[3], *ae_[3], *We[3], *bb[3], *gg[3], *be[3];
    for (int l = 0; l < 3; l++) {
        int base = 6 + 8 * l;
        W[l]   = (const float*)d_in[base + 0];
        as_[l] = (const float*)d_in[base + 1];
        ad_[l] = (const float*)d_in[base + 2];
        ae_[l] = (const float*)d_in[base + 3];
        We[l]  = (const float*)d_in[base + 4];
        bb[l]  = (const float*)d_in[base + 5];
        gg[l]  = (const float*)d_in[base + 6];
        be[l]  = (const float*)d_in[base + 7];
    }
    const float* gW1 = (const float*)d_in[30];
    const float* gb1 = (const float*)d_in[31];
    const float* gW2 = (const float*)d_in[32];
    const float* gb2 = (const float*)d_in[33];
    const float* cW1 = (const float*)d_in[34];
    const float* cb1 = (const float*)d_in[35];
    const float* cW2 = (const float*)d_in[36];
    const float* cb2 = (const float*)d_in[37];
    float* out = (float*)d_out;

    char* p = (char*)d_ws;
    auto take = [&](size_t bytes) -> char* {
        char* r = p;
        p += (bytes + 255) & ~(size_t)255;
        return r;
    };
    float* h0      = (float*)take((size_t)N_NODES * HID * 4);
    float* h1      = (float*)take((size_t)N_NODES * HID * 4);
    float* xp      = (float*)take((size_t)N_NODES * HID * 4);
    float* al_src  = (float*)take((size_t)N_NODES * 4 * 4);
    float* al_dst  = (float*)take((size_t)N_NODES * 4 * 4);
    float* al_edge = (float*)take((size_t)N_EDGES * 4 * 4);
    int*   deg     = (int*)take((size_t)N_NODES * 4);
    int*   offs    = (int*)take((size_t)(N_NODES + 1) * 4);
    int*   pos     = (int*)take((size_t)N_NODES * 4);
    int*   eidx    = (int*)take((size_t)N_EDGES * 4);
    float* WeAe    = (float*)take(ED * 4 * 4);
    float* gate    = (float*)take((size_t)N_NODES * 4);
    float* watt    = (float*)take((size_t)N_NODES * 4);
    float* gmax    = (float*)take(NB * 4);
    float* gden    = (float*)take(NB * 4);
    int*   goff    = (int*)take((NB + 1) * 4);
    float* pooled  = (float*)take(NB * HID * 4);

    const int* src = ei;
    const int* dst = ei + N_EDGES;

    hipMemsetAsync(deg, 0, (size_t)N_NODES * 4, stream);
    hipMemsetAsync(pooled, 0, (size_t)NB * HID * 4, stream);

    k_proj<<<N_NODES, HID, 0, stream>>>(x, pW, pb, h0);
    k_deg<<<(N_EDGES + 255) / 256, 256, 0, stream>>>(dst, deg);
    k_scan<<<1, 1024, 0, stream>>>(deg, offs);
    k_pos<<<(N_NODES + 255) / 256, 256, 0, stream>>>(offs, pos);
    k_scatter<<<(N_EDGES + 255) / 256, 256, 0, stream>>>(dst, pos, eidx);

    float* hc = h0;
    float* hn = h1;
    for (int l = 0; l < 3; l++) {
        if (l < 2) {
            k_node_proj<4><<<N_NODES, HID, 0, stream>>>(hc, W[l], as_[l], ad_[l], xp, al_src, al_dst);
            k_weae<4><<<1, 64, 0, stream>>>(We[l], ae_[l], WeAe);
            k_edge_al<4><<<(N_EDGES + 255) / 256, 256, 0, stream>>>(ea, WeAe, al_edge);
            k_node_agg<4><<<(N_NODES + 3) / 4, 256, 0, stream>>>(src, offs, eidx, xp, al_src,
                                                                 al_dst, al_edge, bb[l], gg[l],
                                                                 be[l], hc, hn);
        } else {
            k_node_proj<1><<<N_NODES, HID, 0, stream>>>(hc, W[l], as_[l], ad_[l], xp, al_src, al_dst);
            k_weae<1><<<1, 64, 0, stream>>>(We[l], ae_[l], WeAe);
            k_edge_al<1><<<(N_EDGES + 255) / 256, 256, 0, stream>>>(ea, WeAe, al_edge);
            k_node_agg<1><<<(N_NODES + 3) / 4, 256, 0, stream>>>(src, offs, eidx, xp, al_src,
                                                                 al_dst, al_edge, bb[l], gg[l],
                                                                 be[l], hc, hn);
        }
        float* t = hc; hc = hn; hn = t;
    }

    k_gate<<<N_NODES, 64, 0, stream>>>(hc, gW1, gb1, gW2, gb2, gate);
    k_bounds<<<(N_NODES + 255) / 256, 256, 0, stream>>>(batch, goff);
    k_gmaxden<<<NB, 256, 0, stream>>>(gate, goff, gmax, gden);
    k_watt<<<(N_NODES + 255) / 256, 256, 0, stream>>>(gate, batch, gmax, gden, watt);
    k_pool<<<dim3(NB, POOL_SPLIT), HID, 0, stream>>>(hc, watt, goff, pooled);
    k_head<<<NB, 64, 0, stream>>>(pooled, cW1, cb1, cW2, cb2, out);
}

// Round 3
// 843.602 us; speedup vs baseline: 1.8331x; 1.8331x over previous
//
#include <hip/hip_runtime.h>
#include <math.h>

#define N_NODES 50000
#define N_EDGES 800000
#define NB      64
#define ND      64
#define ED      16
#define HID     128
#define NC      6
#define POOL_SPLIT 16

__device__ __forceinline__ float wave_sum(float v) {
    #pragma unroll
    for (int o = 32; o > 0; o >>= 1) v += __shfl_xor(v, o, 64);
    return v;
}

// ---------------- h0 = relu(x @ pW + pb), tiled: 8 nodes/block ----------------
__global__ void k_proj(const float* __restrict__ x, const float* __restrict__ pW,
                       const float* __restrict__ pb, float* __restrict__ h) {
    __shared__ float xs[8][ND];
    int tid = threadIdx.x;             // 256
    int base = blockIdx.x * 8;
    for (int idx = tid; idx < 8 * ND; idx += 256) {
        int nn = idx >> 6, k = idx & 63;
        xs[nn][k] = x[(size_t)(base + nn) * ND + k];
    }
    __syncthreads();
    int c = tid & 127;
    int grp = tid >> 7;                // 0,1 -> nodes grp*4..grp*4+3
    float acc[4] = {0.f, 0.f, 0.f, 0.f};
    #pragma unroll 8
    for (int k = 0; k < ND; k++) {
        float wv = pW[k * HID + c];
        #pragma unroll
        for (int q = 0; q < 4; q++) acc[q] += xs[grp * 4 + q][k] * wv;
    }
    float bv = pb[c];
    #pragma unroll
    for (int q = 0; q < 4; q++)
        h[(size_t)(base + grp * 4 + q) * HID + c] = fmaxf(acc[q] + bv, 0.f);
}

// ---------------- CSR build ----------------
__global__ void k_deg(const int* __restrict__ dst, int* __restrict__ deg) {
    int e = blockIdx.x * blockDim.x + threadIdx.x;
    if (e < N_EDGES) atomicAdd(&deg[dst[e]], 1);
}

__global__ void k_scan(const int* __restrict__ deg, int* __restrict__ offs) {
    __shared__ int sums[1024];
    int t = threadIdx.x;
    const int CH = (N_NODES + 1023) / 1024;  // 49
    int start = t * CH, end = min(start + CH, N_NODES);
    int s = 0;
    for (int i = start; i < end; i++) s += deg[i];
    sums[t] = s;
    __syncthreads();
    for (int o = 1; o < 1024; o <<= 1) {
        int v = (t >= o) ? sums[t - o] : 0;
        __syncthreads();
        sums[t] += v;
        __syncthreads();
    }
    int run = (t == 0) ? 0 : sums[t - 1];
    for (int i = start; i < end; i++) { offs[i] = run; run += deg[i]; }
    if (t == 1023) offs[N_NODES] = sums[1023];
}

__global__ void k_pos(const int* __restrict__ offs, int* __restrict__ pos) {
    int n = blockIdx.x * blockDim.x + threadIdx.x;
    if (n < N_NODES) pos[n] = offs[n];
}

__global__ void k_scatter(const int* __restrict__ dst, int* __restrict__ pos,
                          int* __restrict__ eidx) {
    int e = blockIdx.x * blockDim.x + threadIdx.x;
    if (e < N_EDGES) {
        int p = atomicAdd(&pos[dst[e]], 1);
        eidx[p] = e;
    }
}

__global__ void k_csr_cols(const int* __restrict__ eidx, const int* __restrict__ src,
                           const int* __restrict__ dst, int* __restrict__ src_csr,
                           int* __restrict__ dst_csr) {
    int i = blockIdx.x * blockDim.x + threadIdx.x;
    if (i < N_EDGES) {
        int e = eidx[i];
        src_csr[i] = src[e];
        dst_csr[i] = dst[e];
    }
}

// ---------------- per-layer: xp = h@W, al_src/al_dst; tiled 8 nodes/block ----------------
template <int H>
__global__ void k_node_proj(const float* __restrict__ h, const float* __restrict__ W,
                            const float* __restrict__ as_, const float* __restrict__ ad_,
                            float* __restrict__ xp, float* __restrict__ al_src,
                            float* __restrict__ al_dst) {
    __shared__ float hs[8][HID];
    __shared__ float red_s[4][4];
    __shared__ float red_d[4][4];
    int tid = threadIdx.x;             // 256
    int base = blockIdx.x * 8;
    for (int idx = tid; idx < 8 * HID; idx += 256) {
        int nn = idx >> 7, k = idx & 127;
        hs[nn][k] = h[(size_t)(base + nn) * HID + k];
    }
    __syncthreads();
    int c = tid & 127;
    int grp = tid >> 7;                // 0,1
    float acc[4] = {0.f, 0.f, 0.f, 0.f};
    #pragma unroll 8
    for (int k = 0; k < HID; k++) {
        float wv = W[k * HID + c];
        #pragma unroll
        for (int q = 0; q < 4; q++) acc[q] += hs[grp * 4 + q][k] * wv;
    }
    #pragma unroll
    for (int q = 0; q < 4; q++)
        xp[(size_t)(base + grp * 4 + q) * HID + c] = acc[q];
    float av = as_[c], dv = ad_[c];
    float rs[4], rd[4];
    #pragma unroll
    for (int q = 0; q < 4; q++) { rs[q] = acc[q] * av; rd[q] = acc[q] * dv; }
    if (H == 4) {
        #pragma unroll
        for (int o = 16; o > 0; o >>= 1) {
            #pragma unroll
            for (int q = 0; q < 4; q++) {
                rs[q] += __shfl_xor(rs[q], o, 64);
                rd[q] += __shfl_xor(rd[q], o, 64);
            }
        }
        if ((c & 31) == 0) {
            int head = c >> 5;
            #pragma unroll
            for (int q = 0; q < 4; q++) {
                int n = base + grp * 4 + q;
                al_src[n * 4 + head] = rs[q];
                al_dst[n * 4 + head] = rd[q];
            }
        }
    } else {
        #pragma unroll
        for (int o = 32; o > 0; o >>= 1) {
            #pragma unroll
            for (int q = 0; q < 4; q++) {
                rs[q] += __shfl_xor(rs[q], o, 64);
                rd[q] += __shfl_xor(rd[q], o, 64);
            }
        }
        int wave = tid >> 6;
        if ((tid & 63) == 0) {
            #pragma unroll
            for (int q = 0; q < 4; q++) { red_s[wave][q] = rs[q]; red_d[wave][q] = rd[q]; }
        }
        __syncthreads();
        if (tid < 8) {
            int gg = tid >> 2, q = tid & 3;
            int n = base + gg * 4 + q;
            al_src[n] = red_s[gg * 2][q] + red_s[gg * 2 + 1][q];
            al_dst[n] = red_d[gg * 2][q] + red_d[gg * 2 + 1][q];
        }
    }
}

// ---------------- WeAe[k][h] = sum_c We[k, h*C+c] * ae[h,c]  (16 x H) ----------------
template <int H>
__global__ void k_weae(const float* __restrict__ We, const float* __restrict__ ae,
                       float* __restrict__ WeAe) {
    const int C = HID / H;
    int t = threadIdx.x;
    if (t < ED * H) {
        int k = t / H, hh = t % H;
        float s = 0.f;
        for (int cc = 0; cc < C; cc++)
            s += We[k * HID + hh * C + cc] * ae[hh * C + cc];
        WeAe[k * H + hh] = s;
    }
}

// ---------------- w_csr[i][h] = exp(lrelu(al_src+al_dst+ea@WeAe)), CSR order ----------------
// No max-subtraction: logits are O(10) here, exp is fp32-safe and matches ref math.
template <int H>
__global__ void k_edge_w(const int* __restrict__ eidx, const int* __restrict__ src_csr,
                         const int* __restrict__ dst_csr, const float* __restrict__ ea,
                         const float* __restrict__ WeAe, const float* __restrict__ al_src,
                         const float* __restrict__ al_dst, float* __restrict__ w_csr) {
    __shared__ float w[ED * H];
    int tid = threadIdx.x;
    if (tid < ED * H) w[tid] = WeAe[tid];
    __syncthreads();
    int i = blockIdx.x * blockDim.x + tid;
    if (i >= N_EDGES) return;
    int e = eidx[i];
    int s = src_csr[i];
    int n = dst_csr[i];
    float ev[ED];
    const float4* ep4 = reinterpret_cast<const float4*>(ea + (size_t)e * ED);
    #pragma unroll
    for (int q = 0; q < 4; q++) {
        float4 v = ep4[q];
        ev[q * 4 + 0] = v.x; ev[q * 4 + 1] = v.y;
        ev[q * 4 + 2] = v.z; ev[q * 4 + 3] = v.w;
    }
    if (H == 4) {
        float4 wv;
        float* wp = &wv.x;
        #pragma unroll
        for (int hh = 0; hh < 4; hh++) {
            float al = al_src[s * 4 + hh] + al_dst[n * 4 + hh];
            #pragma unroll
            for (int k = 0; k < ED; k++) al += ev[k] * w[k * 4 + hh];
            al = (al >= 0.f) ? al : 0.2f * al;
            wp[hh] = __expf(al);
        }
        *reinterpret_cast<float4*>(w_csr + (size_t)i * 4) = wv;
    } else {
        float al = al_src[s] + al_dst[n];
        #pragma unroll
        for (int k = 0; k < ED; k++) al += ev[k] * w[k];
        al = (al >= 0.f) ? al : 0.2f * al;
        w_csr[i] = __expf(al);
    }
}

// ---------------- fused gather: softmax-normalize + bias + LN + ELU + residual ----------------
// half-wave (32 lanes) per node; lane holds channels 4*hl..4*hl+3 (float4)
template <int H>
__global__ void k_node_agg(const int* __restrict__ offs, const int* __restrict__ src_csr,
                           const float* __restrict__ w_csr, const float* __restrict__ xp,
                           const float* __restrict__ bias, const float* __restrict__ g,
                           const float* __restrict__ be, const float* __restrict__ hin,
                           float* __restrict__ hout) {
    const int C = HID / H;
    int tid = threadIdx.x;             // 256 -> 8 half-waves
    int half = tid >> 5;
    int hl = tid & 31;
    int n = blockIdx.x * 8 + half;
    if (n >= N_NODES) return;
    int e0 = offs[n], e1 = offs[n + 1];
    int c = hl * 4;
    const int h = c / C;               // head for this lane's 4 channels (within one head)
    float4 acc = make_float4(0.f, 0.f, 0.f, 0.f);
    float den = 0.f;

    int i = e0;
    int sA = 0; float wA = 0.f;
    if (i < e1) {
        sA = src_csr[i];
        wA = (H == 4) ? w_csr[(size_t)i * 4 + h] : w_csr[i];
    }
    while (i < e1) {
        const float4 xv = *reinterpret_cast<const float4*>(xp + (size_t)sA * HID + c);
        int i1 = i + 1;
        int sB = 0; float wB = 0.f;
        if (i1 < e1) {
            sB = src_csr[i1];
            wB = (H == 4) ? w_csr[(size_t)i1 * 4 + h] : w_csr[i1];
        }
        acc.x += wA * xv.x; acc.y += wA * xv.y;
        acc.z += wA * xv.z; acc.w += wA * xv.w;
        den += wA;
        sA = sB; wA = wB; i = i1;
    }

    float inv = 1.f / (den + 1e-16f);
    const float4 bv = *reinterpret_cast<const float4*>(bias + c);
    float4 v;
    v.x = acc.x * inv + bv.x; v.y = acc.y * inv + bv.y;
    v.z = acc.z * inv + bv.z; v.w = acc.w * inv + bv.w;
    // layernorm across the half-wave (xor offsets <32 stay within the half)
    float s4 = v.x + v.y + v.z + v.w;
    #pragma unroll
    for (int o = 16; o > 0; o >>= 1) s4 += __shfl_xor(s4, o, 64);
    float mean = s4 * (1.f / HID);
    float dx = v.x - mean, dy = v.y - mean, dz = v.z - mean, dw = v.w - mean;
    float q4 = dx * dx + dy * dy + dz * dz + dw * dw;
    #pragma unroll
    for (int o = 16; o > 0; o >>= 1) q4 += __shfl_xor(q4, o, 64);
    float rstd = rsqrtf(q4 * (1.f / HID) + 1e-5f);
    const float4 gv = *reinterpret_cast<const float4*>(g + c);
    const float4 bev = *reinterpret_cast<const float4*>(be + c);
    float4 y;
    y.x = dx * rstd * gv.x + bev.x;
    y.y = dy * rstd * gv.y + bev.y;
    y.z = dz * rstd * gv.z + bev.z;
    y.w = dw * rstd * gv.w + bev.w;
    y.x = (y.x > 0.f) ? y.x : (__expf(y.x) - 1.f);
    y.y = (y.y > 0.f) ? y.y : (__expf(y.y) - 1.f);
    y.z = (y.z > 0.f) ? y.z : (__expf(y.z) - 1.f);
    y.w = (y.w > 0.f) ? y.w : (__expf(y.w) - 1.f);
    const float4 rv = *reinterpret_cast<const float4*>(hin + (size_t)n * HID + c);
    float4 o4;
    o4.x = y.x + rv.x; o4.y = y.y + rv.y; o4.z = y.z + rv.z; o4.w = y.w + rv.w;
    *reinterpret_cast<float4*>(hout + (size_t)n * HID + c) = o4;
}

// ---------------- gate[n] = relu(h@gW1+gb1)@gW2 + gb2, tiled 16 nodes/block ----------------
__global__ void k_gate(const float* __restrict__ h, const float* __restrict__ gW1,
                       const float* __restrict__ gb1, const float* __restrict__ gW2,
                       const float* __restrict__ gb2, float* __restrict__ gate) {
    __shared__ float hs[16][HID];
    int tid = threadIdx.x;             // 256
    int base = blockIdx.x * 16;
    for (int idx = tid; idx < 16 * HID; idx += 256) {
        int nn = idx >> 7, k = idx & 127;
        hs[nn][k] = h[(size_t)(base + nn) * HID + k];
    }
    __syncthreads();
    int c = tid & 63;
    int wave = tid >> 6;               // 0..3 -> nodes wave*4..wave*4+3
    float acc[4] = {0.f, 0.f, 0.f, 0.f};
    #pragma unroll 8
    for (int k = 0; k < HID; k++) {
        float wv = gW1[k * 64 + c];
        #pragma unroll
        for (int q = 0; q < 4; q++) acc[q] += hs[wave * 4 + q][k] * wv;
    }
    float b1 = gb1[c], w2 = gW2[c];
    float p[4];
    #pragma unroll
    for (int q = 0; q < 4; q++) p[q] = fmaxf(acc[q] + b1, 0.f) * w2;
    #pragma unroll
    for (int o = 32; o > 0; o >>= 1) {
        #pragma unroll
        for (int q = 0; q < 4; q++) p[q] += __shfl_xor(p[q], o, 64);
    }
    if (c == 0) {
        float b2 = gb2[0];
        #pragma unroll
        for (int q = 0; q < 4; q++) gate[base + wave * 4 + q] = p[q] + b2;
    }
}

// ---------------- graph boundaries from sorted batch ----------------
__global__ void k_bounds(const int* __restrict__ batch, int* __restrict__ goff) {
    int n = blockIdx.x * blockDim.x + threadIdx.x;
    if (n >= N_NODES) return;
    int cur = batch[n];
    int prev = (n == 0) ? -1 : batch[n - 1];
    for (int g = prev + 1; g <= cur; g++) goff[g] = n;
    if (n == N_NODES - 1) {
        for (int g = cur + 1; g <= NB; g++) goff[g] = N_NODES;
    }
}

__global__ void k_gmaxden(const float* __restrict__ gate, const int* __restrict__ goff,
                          float* __restrict__ gmax, float* __restrict__ gden) {
    int b = blockIdx.x;
    int t = threadIdx.x;               // 256
    __shared__ float red[256];
    int s = goff[b], e = goff[b + 1];
    float m = -__builtin_inff();
    for (int n = s + t; n < e; n += 256) m = fmaxf(m, gate[n]);
    red[t] = m;
    __syncthreads();
    for (int o = 128; o > 0; o >>= 1) { if (t < o) red[t] = fmaxf(red[t], red[t + o]); __syncthreads(); }
    m = red[0];
    __syncthreads();
    float d = 0.f;
    for (int n = s + t; n < e; n += 256) d += __expf(gate[n] - m);
    red[t] = d;
    __syncthreads();
    for (int o = 128; o > 0; o >>= 1) { if (t < o) red[t] += red[t + o]; __syncthreads(); }
    if (t == 0) { gmax[b] = m; gden[b] = red[0]; }
}

__global__ void k_pool(const float* __restrict__ h, const float* __restrict__ gate,
                       const float* __restrict__ gmax, const float* __restrict__ gden,
                       const int* __restrict__ goff, float* __restrict__ pooled) {
    int b = blockIdx.x;
    int part = blockIdx.y;
    int c = threadIdx.x;               // 128
    int s = goff[b], e = goff[b + 1];
    float m = gmax[b];
    float dinv = 1.f / (gden[b] + 1e-16f);
    float acc = 0.f;
    for (int n = s + part; n < e; n += POOL_SPLIT) {
        float att = __expf(gate[n] - m) * dinv;
        acc += att * h[(size_t)n * HID + c];
    }
    atomicAdd(&pooled[b * HID + c], acc);
}

__global__ void k_head(const float* __restrict__ pooled, const float* __restrict__ cW1,
                       const float* __restrict__ cb1, const float* __restrict__ cW2,
                       const float* __restrict__ cb2, float* __restrict__ out) {
    int b = blockIdx.x;
    int t = threadIdx.x;               // 64
    __shared__ float pr[HID];
    __shared__ float tr[64];
    pr[t] = pooled[b * HID + t];
    pr[t + 64] = pooled[b * HID + t + 64];
    __syncthreads();
    float a = cb1[t];
    #pragma unroll 8
    for (int k = 0; k < HID; k++) a += pr[k] * cW1[k * 64 + t];
    tr[t] = fmaxf(a, 0.f);
    __syncthreads();
    if (t < NC) {
        float o = cb2[t];
        #pragma unroll
        for (int k = 0; k < 64; k++) o += tr[k] * cW2[k * NC + t];
        out[b * NC + t] = o;
    }
}

extern "C" void kernel_launch(void* const* d_in, const int* in_sizes, int n_in,
                              void* d_out, int out_size, void* d_ws, size_t ws_size,
                              hipStream_t stream) {
    (void)in_sizes; (void)n_in; (void)out_size; (void)ws_size;
    const float* x     = (const float*)d_in[0];
    const int*   ei    = (const int*)d_in[1];
    const float* ea    = (const float*)d_in[2];
    const int*   batch = (const int*)d_in[3];
    const float* pW    = (const float*)d_in[4];
    const float* pb    = (const float*)d_in[5];
    const float *W[3], *as_[3], *ad_[3], *ae_[3], *We[3], *bb[3], *gg[3], *be[3];
    for (int l = 0; l < 3; l++) {
        int base = 6 + 8 * l;
        W[l]   = (const float*)d_in[base + 0];
        as_[l] = (const float*)d_in[base + 1];
        ad_[l] = (const float*)d_in[base + 2];
        ae_[l] = (const float*)d_in[base + 3];
        We[l]  = (const float*)d_in[base + 4];
        bb[l]  = (const float*)d_in[base + 5];
        gg[l]  = (const float*)d_in[base + 6];
        be[l]  = (const float*)d_in[base + 7];
    }
    const float* gW1 = (const float*)d_in[30];
    const float* gb1 = (const float*)d_in[31];
    const float* gW2 = (const float*)d_in[32];
    const float* gb2 = (const float*)d_in[33];
    const float* cW1 = (const float*)d_in[34];
    const float* cb1 = (const float*)d_in[35];
    const float* cW2 = (const float*)d_in[36];
    const float* cb2 = (const float*)d_in[37];
    float* out = (float*)d_out;

    char* p = (char*)d_ws;
    auto take = [&](size_t bytes) -> char* {
        char* r = p;
        p += (bytes + 255) & ~(size_t)255;
        return r;
    };
    float* h0      = (float*)take((size_t)N_NODES * HID * 4);
    float* h1      = (float*)take((size_t)N_NODES * HID * 4);
    float* xp      = (float*)take((size_t)N_NODES * HID * 4);
    float* al_src  = (float*)take((size_t)N_NODES * 4 * 4);
    float* al_dst  = (float*)take((size_t)N_NODES * 4 * 4);
    float* w_csr   = (float*)take((size_t)N_EDGES * 4 * 4);
    int*   deg     = (int*)take((size_t)N_NODES * 4);
    int*   offs    = (int*)take((size_t)(N_NODES + 1) * 4);
    int*   pos     = (int*)take((size_t)N_NODES * 4);
    int*   eidx    = (int*)take((size_t)N_EDGES * 4);
    int*   src_csr = (int*)take((size_t)N_EDGES * 4);
    int*   dst_csr = (int*)take((size_t)N_EDGES * 4);
    float* WeAe    = (float*)take(ED * 4 * 4);
    float* gate    = (float*)take((size_t)N_NODES * 4);
    float* gmax    = (float*)take(NB * 4);
    float* gden    = (float*)take(NB * 4);
    int*   goff    = (int*)take((NB + 1) * 4);
    float* pooled  = (float*)take(NB * HID * 4);

    const int* src = ei;
    const int* dst = ei + N_EDGES;

    hipMemsetAsync(deg, 0, (size_t)N_NODES * 4, stream);
    hipMemsetAsync(pooled, 0, (size_t)NB * HID * 4, stream);

    k_proj<<<N_NODES / 8, 256, 0, stream>>>(x, pW, pb, h0);
    k_deg<<<(N_EDGES + 255) / 256, 256, 0, stream>>>(dst, deg);
    k_scan<<<1, 1024, 0, stream>>>(deg, offs);
    k_pos<<<(N_NODES + 255) / 256, 256, 0, stream>>>(offs, pos);
    k_scatter<<<(N_EDGES + 255) / 256, 256, 0, stream>>>(dst, pos, eidx);
    k_csr_cols<<<(N_EDGES + 255) / 256, 256, 0, stream>>>(eidx, src, dst, src_csr, dst_csr);

    float* hc = h0;
    float* hn = h1;
    for (int l = 0; l < 3; l++) {
        if (l < 2) {
            k_node_proj<4><<<N_NODES / 8, 256, 0, stream>>>(hc, W[l], as_[l], ad_[l], xp, al_src, al_dst);
            k_weae<4><<<1, 64, 0, stream>>>(We[l], ae_[l], WeAe);
            k_edge_w<4><<<(N_EDGES + 255) / 256, 256, 0, stream>>>(eidx, src_csr, dst_csr, ea,
                                                                   WeAe, al_src, al_dst, w_csr);
            k_node_agg<4><<<(N_NODES + 7) / 8, 256, 0, stream>>>(offs, src_csr, w_csr, xp,
                                                                 bb[l], gg[l], be[l], hc, hn);
        } else {
            k_node_proj<1><<<N_NODES / 8, 256, 0, stream>>>(hc, W[l], as_[l], ad_[l], xp, al_src, al_dst);
            k_weae<1><<<1, 64, 0, stream>>>(We[l], ae_[l], WeAe);
            k_edge_w<1><<<(N_EDGES + 255) / 256, 256, 0, stream>>>(eidx, src_csr, dst_csr, ea,
                                                                   WeAe, al_src, al_dst, w_csr);
            k_node_agg<1><<<(N_NODES + 7) / 8, 256, 0, stream>>>(offs, src_csr, w_csr, xp,
                                                                 bb[l], gg[l], be[l], hc, hn);
        }
        float* t = hc; hc = hn; hn = t;
    }

    k_gate<<<N_NODES / 16, 256, 0, stream>>>(hc, gW1, gb1, gW2, gb2, gate);
    k_bounds<<<(N_NODES + 255) / 256, 256, 0, stream>>>(batch, goff);
    k_gmaxden<<<NB, 256, 0, stream>>>(gate, goff, gmax, gden);
    k_pool<<<dim3(NB, POOL_SPLIT), HID, 0, stream>>>(hc, gate, gmax, gden, goff, pooled);
    k_head<<<NB, 64, 0, stream>>>(pooled, cW1, cb1, cW2, cb2, out);
}

// Round 4
// 716.990 us; speedup vs baseline: 2.1568x; 1.1766x over previous
//
#include <hip/hip_runtime.h>
#include <math.h>

#define N_NODES 50000
#define N_EDGES 800000
#define NB      64
#define ND      64
#define ED      16
#define HID     128
#define NC      6
#define POOL_SPLIT 16
#define SCAN_BLOCKS ((N_NODES + 255) / 256)   // 196

__device__ __forceinline__ float wave_sum(float v) {
    #pragma unroll
    for (int o = 32; o > 0; o >>= 1) v += __shfl_xor(v, o, 64);
    return v;
}

// ---------------- h0 = relu(x @ pW + pb), tiled: 8 nodes/block ----------------
__global__ void k_proj(const float* __restrict__ x, const float* __restrict__ pW,
                       const float* __restrict__ pb, float* __restrict__ h) {
    __shared__ float xs[8][ND];
    int tid = threadIdx.x;             // 256
    int base = blockIdx.x * 8;
    for (int idx = tid; idx < 8 * ND; idx += 256) {
        int nn = idx >> 6, k = idx & 63;
        xs[nn][k] = x[(size_t)(base + nn) * ND + k];
    }
    __syncthreads();
    int c = tid & 127;
    int grp = tid >> 7;
    float acc[4] = {0.f, 0.f, 0.f, 0.f};
    #pragma unroll 8
    for (int k = 0; k < ND; k++) {
        float wv = pW[k * HID + c];
        #pragma unroll
        for (int q = 0; q < 4; q++) acc[q] += xs[grp * 4 + q][k] * wv;
    }
    float bv = pb[c];
    #pragma unroll
    for (int q = 0; q < 4; q++)
        h[(size_t)(base + grp * 4 + q) * HID + c] = fmaxf(acc[q] + bv, 0.f);
}

// ---------------- CSR build ----------------
__global__ void k_deg(const int* __restrict__ dst, int* __restrict__ deg) {
    int e = blockIdx.x * blockDim.x + threadIdx.x;
    if (e < N_EDGES) atomicAdd(&deg[dst[e]], 1);
}

// phase A: per-block sums
__global__ void k_scanA(const int* __restrict__ deg, int* __restrict__ bsum) {
    __shared__ int wsu[4];
    int t = threadIdx.x;
    int i = blockIdx.x * 256 + t;
    int d = (i < N_NODES) ? deg[i] : 0;
    int v = d;
    #pragma unroll
    for (int o = 32; o > 0; o >>= 1) v += __shfl_xor(v, o, 64);
    if ((t & 63) == 0) wsu[t >> 6] = v;
    __syncthreads();
    if (t == 0) bsum[blockIdx.x] = wsu[0] + wsu[1] + wsu[2] + wsu[3];
}

// phase B: exclusive scan of block sums (196 entries, one block)
__global__ void k_scanB(const int* __restrict__ bsum, int* __restrict__ bpre,
                        int* __restrict__ offs) {
    __shared__ int sc[256];
    int t = threadIdx.x;
    int d = (t < SCAN_BLOCKS) ? bsum[t] : 0;
    sc[t] = d;
    __syncthreads();
    for (int o = 1; o < 256; o <<= 1) {
        int v = (t >= o) ? sc[t - o] : 0;
        __syncthreads();
        sc[t] += v;
        __syncthreads();
    }
    if (t < SCAN_BLOCKS) bpre[t] = sc[t] - d;
    if (t == 0) offs[N_NODES] = N_EDGES;
}

// phase C: block-local exclusive scan + block prefix -> offs, pos
__global__ void k_scanC(const int* __restrict__ deg, const int* __restrict__ bpre,
                        int* __restrict__ offs, int* __restrict__ pos) {
    __shared__ int sc[256];
    int t = threadIdx.x;
    int i = blockIdx.x * 256 + t;
    int d = (i < N_NODES) ? deg[i] : 0;
    sc[t] = d;
    __syncthreads();
    for (int o = 1; o < 256; o <<= 1) {
        int v = (t >= o) ? sc[t - o] : 0;
        __syncthreads();
        sc[t] += v;
        __syncthreads();
    }
    if (i < N_NODES) {
        int off = bpre[blockIdx.x] + sc[t] - d;
        offs[i] = off;
        pos[i] = off;
    }
}

// scatter: fill CSR columns + permutation
__global__ void k_scatter(const int* __restrict__ src, const int* __restrict__ dst,
                          int* __restrict__ pos, int* __restrict__ src_csr,
                          int* __restrict__ dst_csr, int* __restrict__ perm) {
    int e = blockIdx.x * blockDim.x + threadIdx.x;
    if (e < N_EDGES) {
        int d = dst[e];
        int s = src[e];
        int p = atomicAdd(&pos[d], 1);
        src_csr[p] = s;
        dst_csr[p] = d;
        perm[e] = p;
    }
}

// ---------------- WeAe for all 3 layers: [16][9] (4+4+1) ----------------
__global__ void k_weae_all(const float* __restrict__ We0, const float* __restrict__ ae0,
                           const float* __restrict__ We1, const float* __restrict__ ae1,
                           const float* __restrict__ We2, const float* __restrict__ ae2,
                           float* __restrict__ WeAe) {
    int t = threadIdx.x;
    if (t < 64) {                      // layer 0, C=32
        int k = t >> 2, h = t & 3;
        float s = 0.f;
        for (int c = 0; c < 32; c++) s += We0[k * HID + h * 32 + c] * ae0[h * 32 + c];
        WeAe[k * 9 + h] = s;
    } else if (t < 128) {              // layer 1, C=32
        int tt = t - 64;
        int k = tt >> 2, h = tt & 3;
        float s = 0.f;
        for (int c = 0; c < 32; c++) s += We1[k * HID + h * 32 + c] * ae1[h * 32 + c];
        WeAe[k * 9 + 4 + h] = s;
    } else if (t < 144) {              // layer 2, C=128
        int k = t - 128;
        float s = 0.f;
        for (int c = 0; c < HID; c++) s += We2[k * HID + c] * ae2[c];
        WeAe[k * 9 + 8] = s;
    }
}

// ---------------- one coalesced pass over ea: all 3 layers' edge logits, scattered to CSR ----------------
__global__ void k_edge_al_all(const float* __restrict__ ea, const int* __restrict__ perm,
                              const float* __restrict__ WeAe, float* __restrict__ al0,
                              float* __restrict__ al1, float* __restrict__ al2) {
    __shared__ float w[ED * 9];
    int tid = threadIdx.x;
    if (tid < ED * 9) w[tid] = WeAe[tid];
    __syncthreads();
    int e = blockIdx.x * blockDim.x + tid;
    if (e >= N_EDGES) return;
    float ev[ED];
    const float4* ep4 = reinterpret_cast<const float4*>(ea + (size_t)e * ED);
    #pragma unroll
    for (int q = 0; q < 4; q++) {
        float4 v = ep4[q];
        ev[q * 4 + 0] = v.x; ev[q * 4 + 1] = v.y;
        ev[q * 4 + 2] = v.z; ev[q * 4 + 3] = v.w;
    }
    float r[9];
    #pragma unroll
    for (int j = 0; j < 9; j++) r[j] = 0.f;
    #pragma unroll
    for (int k = 0; k < ED; k++) {
        float evk = ev[k];
        #pragma unroll
        for (int j = 0; j < 9; j++) r[j] += evk * w[k * 9 + j];
    }
    int p = perm[e];
    *reinterpret_cast<float4*>(al0 + (size_t)p * 4) = make_float4(r[0], r[1], r[2], r[3]);
    *reinterpret_cast<float4*>(al1 + (size_t)p * 4) = make_float4(r[4], r[5], r[6], r[7]);
    al2[p] = r[8];
}

// ---------------- per-layer: xp = h@W, al_src/al_dst; tiled 8 nodes/block ----------------
template <int H>
__global__ void k_node_proj(const float* __restrict__ h, const float* __restrict__ W,
                            const float* __restrict__ as_, const float* __restrict__ ad_,
                            float* __restrict__ xp, float* __restrict__ al_src,
                            float* __restrict__ al_dst) {
    __shared__ float hs[8][HID];
    __shared__ float red_s[4][4];
    __shared__ float red_d[4][4];
    int tid = threadIdx.x;             // 256
    int base = blockIdx.x * 8;
    for (int idx = tid; idx < 8 * HID; idx += 256) {
        int nn = idx >> 7, k = idx & 127;
        hs[nn][k] = h[(size_t)(base + nn) * HID + k];
    }
    __syncthreads();
    int c = tid & 127;
    int grp = tid >> 7;
    float acc[4] = {0.f, 0.f, 0.f, 0.f};
    #pragma unroll 8
    for (int k = 0; k < HID; k++) {
        float wv = W[k * HID + c];
        #pragma unroll
        for (int q = 0; q < 4; q++) acc[q] += hs[grp * 4 + q][k] * wv;
    }
    #pragma unroll
    for (int q = 0; q < 4; q++)
        xp[(size_t)(base + grp * 4 + q) * HID + c] = acc[q];
    float av = as_[c], dv = ad_[c];
    float rs[4], rd[4];
    #pragma unroll
    for (int q = 0; q < 4; q++) { rs[q] = acc[q] * av; rd[q] = acc[q] * dv; }
    if (H == 4) {
        #pragma unroll
        for (int o = 16; o > 0; o >>= 1) {
            #pragma unroll
            for (int q = 0; q < 4; q++) {
                rs[q] += __shfl_xor(rs[q], o, 64);
                rd[q] += __shfl_xor(rd[q], o, 64);
            }
        }
        if ((c & 31) == 0) {
            int head = c >> 5;
            #pragma unroll
            for (int q = 0; q < 4; q++) {
                int n = base + grp * 4 + q;
                al_src[n * 4 + head] = rs[q];
                al_dst[n * 4 + head] = rd[q];
            }
        }
    } else {
        #pragma unroll
        for (int o = 32; o > 0; o >>= 1) {
            #pragma unroll
            for (int q = 0; q < 4; q++) {
                rs[q] += __shfl_xor(rs[q], o, 64);
                rd[q] += __shfl_xor(rd[q], o, 64);
            }
        }
        int wave = tid >> 6;
        if ((tid & 63) == 0) {
            #pragma unroll
            for (int q = 0; q < 4; q++) { red_s[wave][q] = rs[q]; red_d[wave][q] = rd[q]; }
        }
        __syncthreads();
        if (tid < 8) {
            int gg = tid >> 2, q = tid & 3;
            int n = base + gg * 4 + q;
            al_src[n] = red_s[gg * 2][q] + red_s[gg * 2 + 1][q];
            al_dst[n] = red_d[gg * 2][q] + red_d[gg * 2 + 1][q];
        }
    }
}

// ---------------- w_csr = exp(lrelu(al_src+al_dst+al_edge)), all coalesced except 16B gathers ----------------
template <int H>
__global__ void k_edge_w(const int* __restrict__ src_csr, const int* __restrict__ dst_csr,
                         const float* __restrict__ al_e, const float* __restrict__ al_src,
                         const float* __restrict__ al_dst, float* __restrict__ w_csr) {
    int i = blockIdx.x * blockDim.x + threadIdx.x;
    if (i >= N_EDGES) return;
    int s = src_csr[i];
    int n = dst_csr[i];
    if (H == 4) {
        float4 ae4 = *reinterpret_cast<const float4*>(al_e + (size_t)i * 4);
        float4 sa  = *reinterpret_cast<const float4*>(al_src + (size_t)s * 4);
        float4 da  = *reinterpret_cast<const float4*>(al_dst + (size_t)n * 4);
        float4 wv;
        float al;
        al = sa.x + da.x + ae4.x; al = (al >= 0.f) ? al : 0.2f * al; wv.x = __expf(al);
        al = sa.y + da.y + ae4.y; al = (al >= 0.f) ? al : 0.2f * al; wv.y = __expf(al);
        al = sa.z + da.z + ae4.z; al = (al >= 0.f) ? al : 0.2f * al; wv.z = __expf(al);
        al = sa.w + da.w + ae4.w; al = (al >= 0.f) ? al : 0.2f * al; wv.w = __expf(al);
        *reinterpret_cast<float4*>(w_csr + (size_t)i * 4) = wv;
    } else {
        float al = al_src[s] + al_dst[n] + al_e[i];
        al = (al >= 0.f) ? al : 0.2f * al;
        w_csr[i] = __expf(al);
    }
}

// ---------------- fused gather: wave/node, halves process alternate edges ----------------
template <int H>
__global__ void k_node_agg(const int* __restrict__ offs, const int* __restrict__ src_csr,
                           const float* __restrict__ w_csr, const float* __restrict__ xp,
                           const float* __restrict__ bias, const float* __restrict__ g,
                           const float* __restrict__ be, const float* __restrict__ hin,
                           float* __restrict__ hout) {
    const int C = HID / H;
    int tid = threadIdx.x;             // 256 -> 4 waves
    int wave = tid >> 6;
    int lane = tid & 63;
    int n = blockIdx.x * 4 + wave;
    if (n >= N_NODES) return;
    int e0 = offs[n], e1 = offs[n + 1];
    int half = lane >> 5;
    int hl = lane & 31;
    int c = hl * 4;
    const int h = c / C;
    float4 acc = make_float4(0.f, 0.f, 0.f, 0.f);
    float den = 0.f;

    int i = e0 + half;
    int sA = 0; float wA = 0.f;
    if (i < e1) {
        sA = src_csr[i];
        wA = (H == 4) ? w_csr[(size_t)i * 4 + h] : w_csr[i];
    }
    while (i < e1) {
        const float4 xv = *reinterpret_cast<const float4*>(xp + (size_t)sA * HID + c);
        int i2 = i + 2;
        int sB = 0; float wB = 0.f;
        if (i2 < e1) {
            sB = src_csr[i2];
            wB = (H == 4) ? w_csr[(size_t)i2 * 4 + h] : w_csr[i2];
        }
        acc.x += wA * xv.x; acc.y += wA * xv.y;
        acc.z += wA * xv.z; acc.w += wA * xv.w;
        den += wA;
        sA = sB; wA = wB; i = i2;
    }
    // combine the two halves (same channels)
    acc.x += __shfl_xor(acc.x, 32, 64);
    acc.y += __shfl_xor(acc.y, 32, 64);
    acc.z += __shfl_xor(acc.z, 32, 64);
    acc.w += __shfl_xor(acc.w, 32, 64);
    den   += __shfl_xor(den,   32, 64);

    float inv = 1.f / (den + 1e-16f);
    const float4 bv = *reinterpret_cast<const float4*>(bias + c);
    float4 v;
    v.x = acc.x * inv + bv.x; v.y = acc.y * inv + bv.y;
    v.z = acc.z * inv + bv.z; v.w = acc.w * inv + bv.w;
    float s4 = v.x + v.y + v.z + v.w;
    #pragma unroll
    for (int o = 16; o > 0; o >>= 1) s4 += __shfl_xor(s4, o, 64);
    float mean = s4 * (1.f / HID);
    float dx = v.x - mean, dy = v.y - mean, dz = v.z - mean, dw = v.w - mean;
    float q4 = dx * dx + dy * dy + dz * dz + dw * dw;
    #pragma unroll
    for (int o = 16; o > 0; o >>= 1) q4 += __shfl_xor(q4, o, 64);
    float rstd = rsqrtf(q4 * (1.f / HID) + 1e-5f);
    if (half == 0) {
        const float4 gv  = *reinterpret_cast<const float4*>(g + c);
        const float4 bev = *reinterpret_cast<const float4*>(be + c);
        float4 y;
        y.x = dx * rstd * gv.x + bev.x;
        y.y = dy * rstd * gv.y + bev.y;
        y.z = dz * rstd * gv.z + bev.z;
        y.w = dw * rstd * gv.w + bev.w;
        y.x = (y.x > 0.f) ? y.x : (__expf(y.x) - 1.f);
        y.y = (y.y > 0.f) ? y.y : (__expf(y.y) - 1.f);
        y.z = (y.z > 0.f) ? y.z : (__expf(y.z) - 1.f);
        y.w = (y.w > 0.f) ? y.w : (__expf(y.w) - 1.f);
        const float4 rv = *reinterpret_cast<const float4*>(hin + (size_t)n * HID + c);
        float4 o4;
        o4.x = y.x + rv.x; o4.y = y.y + rv.y; o4.z = y.z + rv.z; o4.w = y.w + rv.w;
        *reinterpret_cast<float4*>(hout + (size_t)n * HID + c) = o4;
    }
}

// ---------------- gate[n] = relu(h@gW1+gb1)@gW2 + gb2, tiled 16 nodes/block ----------------
__global__ void k_gate(const float* __restrict__ h, const float* __restrict__ gW1,
                       const float* __restrict__ gb1, const float* __restrict__ gW2,
                       const float* __restrict__ gb2, float* __restrict__ gate) {
    __shared__ float hs[16][HID];
    int tid = threadIdx.x;             // 256
    int base = blockIdx.x * 16;
    for (int idx = tid; idx < 16 * HID; idx += 256) {
        int nn = idx >> 7, k = idx & 127;
        hs[nn][k] = h[(size_t)(base + nn) * HID + k];
    }
    __syncthreads();
    int c = tid & 63;
    int wave = tid >> 6;
    float acc[4] = {0.f, 0.f, 0.f, 0.f};
    #pragma unroll 8
    for (int k = 0; k < HID; k++) {
        float wv = gW1[k * 64 + c];
        #pragma unroll
        for (int q = 0; q < 4; q++) acc[q] += hs[wave * 4 + q][k] * wv;
    }
    float b1 = gb1[c], w2 = gW2[c];
    float p[4];
    #pragma unroll
    for (int q = 0; q < 4; q++) p[q] = fmaxf(acc[q] + b1, 0.f) * w2;
    #pragma unroll
    for (int o = 32; o > 0; o >>= 1) {
        #pragma unroll
        for (int q = 0; q < 4; q++) p[q] += __shfl_xor(p[q], o, 64);
    }
    if (c == 0) {
        float b2 = gb2[0];
        #pragma unroll
        for (int q = 0; q < 4; q++) gate[base + wave * 4 + q] = p[q] + b2;
    }
}

// ---------------- graph boundaries from sorted batch ----------------
__global__ void k_bounds(const int* __restrict__ batch, int* __restrict__ goff) {
    int n = blockIdx.x * blockDim.x + threadIdx.x;
    if (n >= N_NODES) return;
    int cur = batch[n];
    int prev = (n == 0) ? -1 : batch[n - 1];
    for (int g = prev + 1; g <= cur; g++) goff[g] = n;
    if (n == N_NODES - 1) {
        for (int g = cur + 1; g <= NB; g++) goff[g] = N_NODES;
    }
}

__global__ void k_gmaxden(const float* __restrict__ gate, const int* __restrict__ goff,
                          float* __restrict__ gmax, float* __restrict__ gden) {
    int b = blockIdx.x;
    int t = threadIdx.x;               // 256
    __shared__ float red[256];
    int s = goff[b], e = goff[b + 1];
    float m = -__builtin_inff();
    for (int n = s + t; n < e; n += 256) m = fmaxf(m, gate[n]);
    red[t] = m;
    __syncthreads();
    for (int o = 128; o > 0; o >>= 1) { if (t < o) red[t] = fmaxf(red[t], red[t + o]); __syncthreads(); }
    m = red[0];
    __syncthreads();
    float d = 0.f;
    for (int n = s + t; n < e; n += 256) d += __expf(gate[n] - m);
    red[t] = d;
    __syncthreads();
    for (int o = 128; o > 0; o >>= 1) { if (t < o) red[t] += red[t + o]; __syncthreads(); }
    if (t == 0) { gmax[b] = m; gden[b] = red[0]; }
}

__global__ void k_pool(const float* __restrict__ h, const float* __restrict__ gate,
                       const float* __restrict__ gmax, const float* __restrict__ gden,
                       const int* __restrict__ goff, float* __restrict__ pooled) {
    int b = blockIdx.x;
    int part = blockIdx.y;
    int c = threadIdx.x;               // 128
    int s = goff[b], e = goff[b + 1];
    float m = gmax[b];
    float dinv = 1.f / (gden[b] + 1e-16f);
    float acc = 0.f;
    for (int n = s + part; n < e; n += POOL_SPLIT) {
        float att = __expf(gate[n] - m) * dinv;
        acc += att * h[(size_t)n * HID + c];
    }
    atomicAdd(&pooled[b * HID + c], acc);
}

__global__ void k_head(const float* __restrict__ pooled, const float* __restrict__ cW1,
                       const float* __restrict__ cb1, const float* __restrict__ cW2,
                       const float* __restrict__ cb2, float* __restrict__ out) {
    int b = blockIdx.x;
    int t = threadIdx.x;               // 64
    __shared__ float pr[HID];
    __shared__ float tr[64];
    pr[t] = pooled[b * HID + t];
    pr[t + 64] = pooled[b * HID + t + 64];
    __syncthreads();
    float a = cb1[t];
    #pragma unroll 8
    for (int k = 0; k < HID; k++) a += pr[k] * cW1[k * 64 + t];
    tr[t] = fmaxf(a, 0.f);
    __syncthreads();
    if (t < NC) {
        float o = cb2[t];
        #pragma unroll
        for (int k = 0; k < 64; k++) o += tr[k] * cW2[k * NC + t];
        out[b * NC + t] = o;
    }
}

extern "C" void kernel_launch(void* const* d_in, const int* in_sizes, int n_in,
                              void* d_out, int out_size, void* d_ws, size_t ws_size,
                              hipStream_t stream) {
    (void)in_sizes; (void)n_in; (void)out_size; (void)ws_size;
    const float* x     = (const float*)d_in[0];
    const int*   ei    = (const int*)d_in[1];
    const float* ea    = (const float*)d_in[2];
    const int*   batch = (const int*)d_in[3];
    const float* pW    = (const float*)d_in[4];
    const float* pb    = (const float*)d_in[5];
    const float *W[3], *as_[3], *ad_[3], *ae_[3], *We[3], *bb[3], *gg[3], *be[3];
    for (int l = 0; l < 3; l++) {
        int base = 6 + 8 * l;
        W[l]   = (const float*)d_in[base + 0];
        as_[l] = (const float*)d_in[base + 1];
        ad_[l] = (const float*)d_in[base + 2];
        ae_[l] = (const float*)d_in[base + 3];
        We[l]  = (const float*)d_in[base + 4];
        bb[l]  = (const float*)d_in[base + 5];
        gg[l]  = (const float*)d_in[base + 6];
        be[l]  = (const float*)d_in[base + 7];
    }
    const float* gW1 = (const float*)d_in[30];
    const float* gb1 = (const float*)d_in[31];
    const float* gW2 = (const float*)d_in[32];
    const float* gb2 = (const float*)d_in[33];
    const float* cW1 = (const float*)d_in[34];
    const float* cb1 = (const float*)d_in[35];
    const float* cW2 = (const float*)d_in[36];
    const float* cb2 = (const float*)d_in[37];
    float* out = (float*)d_out;

    char* p = (char*)d_ws;
    auto take = [&](size_t bytes) -> char* {
        char* r = p;
        p += (bytes + 255) & ~(size_t)255;
        return r;
    };
    float* h0      = (float*)take((size_t)N_NODES * HID * 4);
    float* h1      = (float*)take((size_t)N_NODES * HID * 4);
    float* xp      = (float*)take((size_t)N_NODES * HID * 4);
    float* al_src  = (float*)take((size_t)N_NODES * 4 * 4);
    float* al_dst  = (float*)take((size_t)N_NODES * 4 * 4);
    float* w_csr   = (float*)take((size_t)N_EDGES * 4 * 4);
    float* al0     = (float*)take((size_t)N_EDGES * 4 * 4);
    float* al1     = (float*)take((size_t)N_EDGES * 4 * 4);
    float* al2     = (float*)take((size_t)N_EDGES * 4);
    int*   deg     = (int*)take((size_t)N_NODES * 4);
    int*   offs    = (int*)take((size_t)(N_NODES + 1) * 4);
    int*   pos     = (int*)take((size_t)N_NODES * 4);
    int*   src_csr = (int*)take((size_t)N_EDGES * 4);
    int*   dst_csr = (int*)take((size_t)N_EDGES * 4);
    int*   perm    = (int*)take((size_t)N_EDGES * 4);
    int*   bsum    = (int*)take(256 * 4);
    int*   bpre    = (int*)take(256 * 4);
    float* WeAe    = (float*)take(ED * 9 * 4);
    float* gate    = (float*)take((size_t)N_NODES * 4);
    float* gmax    = (float*)take(NB * 4);
    float* gden    = (float*)take(NB * 4);
    int*   goff    = (int*)take((NB + 1) * 4);
    float* pooled  = (float*)take(NB * HID * 4);

    const int* src = ei;
    const int* dst = ei + N_EDGES;

    hipMemsetAsync(deg, 0, (size_t)N_NODES * 4, stream);
    hipMemsetAsync(pooled, 0, (size_t)NB * HID * 4, stream);

    k_proj<<<N_NODES / 8, 256, 0, stream>>>(x, pW, pb, h0);
    k_deg<<<(N_EDGES + 255) / 256, 256, 0, stream>>>(dst, deg);
    k_scanA<<<SCAN_BLOCKS, 256, 0, stream>>>(deg, bsum);
    k_scanB<<<1, 256, 0, stream>>>(bsum, bpre, offs);
    k_scanC<<<SCAN_BLOCKS, 256, 0, stream>>>(deg, bpre, offs, pos);
    k_scatter<<<(N_EDGES + 255) / 256, 256, 0, stream>>>(src, dst, pos, src_csr, dst_csr, perm);
    k_weae_all<<<1, 256, 0, stream>>>(We[0], ae_[0], We[1], ae_[1], We[2], ae_[2], WeAe);
    k_edge_al_all<<<(N_EDGES + 255) / 256, 256, 0, stream>>>(ea, perm, WeAe, al0, al1, al2);

    float* hc = h0;
    float* hn = h1;
    for (int l = 0; l < 3; l++) {
        if (l < 2) {
            const float* alE = (l == 0) ? al0 : al1;
            k_node_proj<4><<<N_NODES / 8, 256, 0, stream>>>(hc, W[l], as_[l], ad_[l], xp, al_src, al_dst);
            k_edge_w<4><<<(N_EDGES + 255) / 256, 256, 0, stream>>>(src_csr, dst_csr, alE,
                                                                   al_src, al_dst, w_csr);
            k_node_agg<4><<<(N_NODES + 3) / 4, 256, 0, stream>>>(offs, src_csr, w_csr, xp,
                                                                 bb[l], gg[l], be[l], hc, hn);
        } else {
            k_node_proj<1><<<N_NODES / 8, 256, 0, stream>>>(hc, W[l], as_[l], ad_[l], xp, al_src, al_dst);
            k_edge_w<1><<<(N_EDGES + 255) / 256, 256, 0, stream>>>(src_csr, dst_csr, al2,
                                                                   al_src, al_dst, w_csr);
            k_node_agg<1><<<(N_NODES + 3) / 4, 256, 0, stream>>>(offs, src_csr, w_csr, xp,
                                                                 bb[l], gg[l], be[l], hc, hn);
        }
        float* t = hc; hc = hn; hn = t;
    }

    k_gate<<<N_NODES / 16, 256, 0, stream>>>(hc, gW1, gb1, gW2, gb2, gate);
    k_bounds<<<(N_NODES + 255) / 256, 256, 0, stream>>>(batch, goff);
    k_gmaxden<<<NB, 256, 0, stream>>>(gate, goff, gmax, gden);
    k_pool<<<dim3(NB, POOL_SPLIT), HID, 0, stream>>>(hc, gate, gmax, gden, goff, pooled);
    k_head<<<NB, 64, 0, stream>>>(pooled, cW1, cb1, cW2, cb2, out);
}

// Round 5
// 633.491 us; speedup vs baseline: 2.4411x; 1.1318x over previous
//
#include <hip/hip_runtime.h>
#include <hip/hip_fp16.h>
#include <math.h>

#define N_NODES 50000
#define N_EDGES 800000
#define NB      64
#define ND      64
#define ED      16
#define HID     128
#define NC      6
#define POOL_SPLIT 16
#define SCAN_BLOCKS ((N_NODES + 255) / 256)   // 196

// ---------------- h0 = relu(x @ pW + pb), tiled: 16 nodes/block ----------------
__global__ void k_proj(const float* __restrict__ x, const float* __restrict__ pW,
                       const float* __restrict__ pb, float* __restrict__ h) {
    __shared__ float xs[16][ND];
    int tid = threadIdx.x;             // 256
    int base = blockIdx.x * 16;
    for (int idx = tid; idx < 16 * ND; idx += 256) {
        int nn = idx >> 6, k = idx & 63;
        xs[nn][k] = x[(size_t)(base + nn) * ND + k];
    }
    __syncthreads();
    int c = tid & 127;
    int grp = tid >> 7;                // 0,1 -> nodes grp*8..grp*8+7
    float acc[8] = {0.f, 0.f, 0.f, 0.f, 0.f, 0.f, 0.f, 0.f};
    #pragma unroll 4
    for (int k = 0; k < ND; k++) {
        float wv = pW[k * HID + c];
        #pragma unroll
        for (int q = 0; q < 8; q++) acc[q] += xs[grp * 8 + q][k] * wv;
    }
    float bv = pb[c];
    #pragma unroll
    for (int q = 0; q < 8; q++)
        h[(size_t)(base + grp * 8 + q) * HID + c] = fmaxf(acc[q] + bv, 0.f);
}

// ---------------- CSR build ----------------
__global__ void k_deg(const int* __restrict__ dst, int* __restrict__ deg) {
    int e = blockIdx.x * blockDim.x + threadIdx.x;
    if (e < N_EDGES) atomicAdd(&deg[dst[e]], 1);
}

__global__ void k_scanA(const int* __restrict__ deg, int* __restrict__ bsum) {
    __shared__ int wsu[4];
    int t = threadIdx.x;
    int i = blockIdx.x * 256 + t;
    int d = (i < N_NODES) ? deg[i] : 0;
    int v = d;
    #pragma unroll
    for (int o = 32; o > 0; o >>= 1) v += __shfl_xor(v, o, 64);
    if ((t & 63) == 0) wsu[t >> 6] = v;
    __syncthreads();
    if (t == 0) bsum[blockIdx.x] = wsu[0] + wsu[1] + wsu[2] + wsu[3];
}

__global__ void k_scanB(const int* __restrict__ bsum, int* __restrict__ bpre,
                        int* __restrict__ offs) {
    __shared__ int sc[256];
    int t = threadIdx.x;
    int d = (t < SCAN_BLOCKS) ? bsum[t] : 0;
    sc[t] = d;
    __syncthreads();
    for (int o = 1; o < 256; o <<= 1) {
        int v = (t >= o) ? sc[t - o] : 0;
        __syncthreads();
        sc[t] += v;
        __syncthreads();
    }
    if (t < SCAN_BLOCKS) bpre[t] = sc[t] - d;
    if (t == 0) offs[N_NODES] = N_EDGES;
}

__global__ void k_scanC(const int* __restrict__ deg, const int* __restrict__ bpre,
                        int* __restrict__ offs, int* __restrict__ pos) {
    __shared__ int sc[256];
    int t = threadIdx.x;
    int i = blockIdx.x * 256 + t;
    int d = (i < N_NODES) ? deg[i] : 0;
    sc[t] = d;
    __syncthreads();
    for (int o = 1; o < 256; o <<= 1) {
        int v = (t >= o) ? sc[t - o] : 0;
        __syncthreads();
        sc[t] += v;
        __syncthreads();
    }
    if (i < N_NODES) {
        int off = bpre[blockIdx.x] + sc[t] - d;
        offs[i] = off;
        pos[i] = off;
    }
}

// ---------------- WeAe for all 3 layers: [16][9] (4+4+1) ----------------
__global__ void k_weae_all(const float* __restrict__ We0, const float* __restrict__ ae0,
                           const float* __restrict__ We1, const float* __restrict__ ae1,
                           const float* __restrict__ We2, const float* __restrict__ ae2,
                           float* __restrict__ WeAe) {
    int t = threadIdx.x;
    if (t < 64) {
        int k = t >> 2, h = t & 3;
        float s = 0.f;
        for (int c = 0; c < 32; c++) s += We0[k * HID + h * 32 + c] * ae0[h * 32 + c];
        WeAe[k * 9 + h] = s;
    } else if (t < 128) {
        int tt = t - 64;
        int k = tt >> 2, h = tt & 3;
        float s = 0.f;
        for (int c = 0; c < 32; c++) s += We1[k * HID + h * 32 + c] * ae1[h * 32 + c];
        WeAe[k * 9 + 4 + h] = s;
    } else if (t < 144) {
        int k = t - 128;
        float s = 0.f;
        for (int c = 0; c < HID; c++) s += We2[k * HID + c] * ae2[c];
        WeAe[k * 9 + 8] = s;
    }
}

// ---------------- build packed CSR records: one 64B line per edge ----------------
// rec[p] (4 x float4): q0={r0..r3}(L0) q1={r4..r7}(L1) q2={r8, src, dst, 0} q3=0
__global__ void k_edge_build(const int* __restrict__ src, const int* __restrict__ dst,
                             const float* __restrict__ ea, const float* __restrict__ WeAe,
                             int* __restrict__ pos, float4* __restrict__ rec) {
    __shared__ float w[ED * 9];
    int tid = threadIdx.x;
    if (tid < ED * 9) w[tid] = WeAe[tid];
    __syncthreads();
    int e = blockIdx.x * blockDim.x + tid;
    if (e >= N_EDGES) return;
    float ev[ED];
    const float4* ep4 = reinterpret_cast<const float4*>(ea + (size_t)e * ED);
    #pragma unroll
    for (int q = 0; q < 4; q++) {
        float4 v = ep4[q];
        ev[q * 4 + 0] = v.x; ev[q * 4 + 1] = v.y;
        ev[q * 4 + 2] = v.z; ev[q * 4 + 3] = v.w;
    }
    float r[9];
    #pragma unroll
    for (int j = 0; j < 9; j++) r[j] = 0.f;
    #pragma unroll
    for (int k = 0; k < ED; k++) {
        float evk = ev[k];
        #pragma unroll
        for (int j = 0; j < 9; j++) r[j] += evk * w[k * 9 + j];
    }
    int d = dst[e];
    int s = src[e];
    int p = atomicAdd(&pos[d], 1);
    size_t b = (size_t)p * 4;
    rec[b + 0] = make_float4(r[0], r[1], r[2], r[3]);
    rec[b + 1] = make_float4(r[4], r[5], r[6], r[7]);
    rec[b + 2] = make_float4(r[8], __int_as_float(s), __int_as_float(d), 0.f);
    rec[b + 3] = make_float4(0.f, 0.f, 0.f, 0.f);
}

// ---------------- per-layer: xp(fp16) = h@W, al_src/al_dst; tiled 16 nodes/block ----------------
template <int H>
__global__ void k_node_proj(const float* __restrict__ h, const float* __restrict__ W,
                            const float* __restrict__ as_, const float* __restrict__ ad_,
                            __half* __restrict__ xp, float* __restrict__ al_src,
                            float* __restrict__ al_dst) {
    __shared__ float hs[16][HID];
    __shared__ float red_s[4][8];
    __shared__ float red_d[4][8];
    int tid = threadIdx.x;             // 256
    int base = blockIdx.x * 16;
    for (int idx = tid; idx < 16 * HID; idx += 256) {
        int nn = idx >> 7, k = idx & 127;
        hs[nn][k] = h[(size_t)(base + nn) * HID + k];
    }
    __syncthreads();
    int c = tid & 127;
    int grp = tid >> 7;                // 0,1 -> nodes grp*8..grp*8+7
    float acc[8] = {0.f, 0.f, 0.f, 0.f, 0.f, 0.f, 0.f, 0.f};
    #pragma unroll 4
    for (int k = 0; k < HID; k++) {
        float wv = W[k * HID + c];
        #pragma unroll
        for (int q = 0; q < 8; q++) acc[q] += hs[grp * 8 + q][k] * wv;
    }
    #pragma unroll
    for (int q = 0; q < 8; q++)
        xp[(size_t)(base + grp * 8 + q) * HID + c] = __float2half_rn(acc[q]);
    float av = as_[c], dv = ad_[c];
    float rs[8], rd[8];
    #pragma unroll
    for (int q = 0; q < 8; q++) { rs[q] = acc[q] * av; rd[q] = acc[q] * dv; }
    if (H == 4) {
        #pragma unroll
        for (int o = 16; o > 0; o >>= 1) {
            #pragma unroll
            for (int q = 0; q < 8; q++) {
                rs[q] += __shfl_xor(rs[q], o, 64);
                rd[q] += __shfl_xor(rd[q], o, 64);
            }
        }
        if ((c & 31) == 0) {
            int head = c >> 5;
            #pragma unroll
            for (int q = 0; q < 8; q++) {
                int n = base + grp * 8 + q;
                al_src[n * 4 + head] = rs[q];
                al_dst[n * 4 + head] = rd[q];
            }
        }
    } else {
        #pragma unroll
        for (int o = 32; o > 0; o >>= 1) {
            #pragma unroll
            for (int q = 0; q < 8; q++) {
                rs[q] += __shfl_xor(rs[q], o, 64);
                rd[q] += __shfl_xor(rd[q], o, 64);
            }
        }
        int wave = tid >> 6;
        if ((tid & 63) == 0) {
            #pragma unroll
            for (int q = 0; q < 8; q++) { red_s[wave][q] = rs[q]; red_d[wave][q] = rd[q]; }
        }
        __syncthreads();
        if (tid < 16) {
            int gg = tid >> 3, q = tid & 7;
            int n = base + gg * 8 + q;
            al_src[n] = red_s[gg * 2][q] + red_s[gg * 2 + 1][q];
            al_dst[n] = red_d[gg * 2][q] + red_d[gg * 2 + 1][q];
        }
    }
}

// ---------------- per-layer edge weights from packed records ----------------
template <int SLOT>    // 0 or 1 (H=4 layers)
__global__ void k_edge_w4(const float4* __restrict__ rec, const float* __restrict__ al_src,
                          const float* __restrict__ al_dst, float4* __restrict__ w_csr,
                          int* __restrict__ src_out) {
    int i = blockIdx.x * blockDim.x + threadIdx.x;
    if (i >= N_EDGES) return;
    float4 r    = rec[(size_t)i * 4 + SLOT];
    float4 meta = rec[(size_t)i * 4 + 2];
    int s = __float_as_int(meta.y);
    int d = __float_as_int(meta.z);
    float4 sa = *reinterpret_cast<const float4*>(al_src + (size_t)s * 4);
    float4 da = *reinterpret_cast<const float4*>(al_dst + (size_t)d * 4);
    float4 wv;
    float al;
    al = sa.x + da.x + r.x; al = (al >= 0.f) ? al : 0.2f * al; wv.x = __expf(al);
    al = sa.y + da.y + r.y; al = (al >= 0.f) ? al : 0.2f * al; wv.y = __expf(al);
    al = sa.z + da.z + r.z; al = (al >= 0.f) ? al : 0.2f * al; wv.z = __expf(al);
    al = sa.w + da.w + r.w; al = (al >= 0.f) ? al : 0.2f * al; wv.w = __expf(al);
    w_csr[i] = wv;
    if (SLOT == 0) src_out[i] = s;
}

__global__ void k_edge_w1(const float4* __restrict__ rec, const float* __restrict__ al_src,
                          const float* __restrict__ al_dst, float* __restrict__ w_csr) {
    int i = blockIdx.x * blockDim.x + threadIdx.x;
    if (i >= N_EDGES) return;
    float4 meta = rec[(size_t)i * 4 + 2];
    int s = __float_as_int(meta.y);
    int d = __float_as_int(meta.z);
    float al = al_src[s] + al_dst[d] + meta.x;
    al = (al >= 0.f) ? al : 0.2f * al;
    w_csr[i] = __expf(al);
}

// ---------------- fused gather: 4 edges in flight/wave, fp16 xp ----------------
template <int H>
__global__ void k_node_agg(const int* __restrict__ offs, const int* __restrict__ src_csr,
                           const float* __restrict__ w_csr, const __half* __restrict__ xp,
                           const float* __restrict__ bias, const float* __restrict__ g,
                           const float* __restrict__ be, const float* __restrict__ hin,
                           float* __restrict__ hout) {
    const int C = HID / H;
    int tid = threadIdx.x;             // 256 -> 4 waves
    int wave = tid >> 6;
    int lane = tid & 63;
    int n = blockIdx.x * 4 + wave;
    if (n >= N_NODES) return;
    int e0 = offs[n], e1 = offs[n + 1];
    int side = lane >> 5;
    int hl = lane & 31;
    int c = hl * 4;
    const int h = c / C;
    float ax = 0.f, ay = 0.f, az = 0.f, aw = 0.f, den = 0.f;

    int i = e0 + side;                 // this side: i, i+2, i+4, ...
    int sA = 0, sB = 0; float wA = 0.f, wB = 0.f;
    if (i < e1)     { sA = src_csr[i];     wA = (H == 4) ? w_csr[(size_t)i * 4 + h]       : w_csr[i]; }
    if (i + 2 < e1) { sB = src_csr[i + 2]; wB = (H == 4) ? w_csr[(size_t)(i + 2) * 4 + h] : w_csr[i + 2]; }
    while (i < e1) {
        uint2 rA = *reinterpret_cast<const uint2*>(xp + (size_t)sA * HID + c);
        uint2 rB = *reinterpret_cast<const uint2*>(xp + (size_t)sB * HID + c);
        int i4 = i + 4, i6 = i + 6;
        int sC = 0, sD = 0; float wC = 0.f, wD = 0.f;
        if (i4 < e1) { sC = src_csr[i4]; wC = (H == 4) ? w_csr[(size_t)i4 * 4 + h] : w_csr[i4]; }
        if (i6 < e1) { sD = src_csr[i6]; wD = (H == 4) ? w_csr[(size_t)i6 * 4 + h] : w_csr[i6]; }
        {
            union { uint2 u; __half2 h2[2]; } t; t.u = rA;
            float2 lo = __half22float2(t.h2[0]), hi = __half22float2(t.h2[1]);
            ax += wA * lo.x; ay += wA * lo.y; az += wA * hi.x; aw += wA * hi.y; den += wA;
        }
        {
            union { uint2 u; __half2 h2[2]; } t; t.u = rB;
            float2 lo = __half22float2(t.h2[0]), hi = __half22float2(t.h2[1]);
            ax += wB * lo.x; ay += wB * lo.y; az += wB * hi.x; aw += wB * hi.y; den += wB;
        }
        sA = sC; wA = wC; sB = sD; wB = wD;
        i += 4;
    }
    // combine sides (same channels)
    ax += __shfl_xor(ax, 32, 64);
    ay += __shfl_xor(ay, 32, 64);
    az += __shfl_xor(az, 32, 64);
    aw += __shfl_xor(aw, 32, 64);
    den += __shfl_xor(den, 32, 64);

    float inv = 1.f / (den + 1e-16f);
    const float4 bv = *reinterpret_cast<const float4*>(bias + c);
    float vx = ax * inv + bv.x, vy = ay * inv + bv.y;
    float vz = az * inv + bv.z, vw = aw * inv + bv.w;
    float s4 = vx + vy + vz + vw;
    #pragma unroll
    for (int o = 16; o > 0; o >>= 1) s4 += __shfl_xor(s4, o, 64);
    float mean = s4 * (1.f / HID);
    float dx = vx - mean, dy = vy - mean, dz = vz - mean, dw = vw - mean;
    float q4 = dx * dx + dy * dy + dz * dz + dw * dw;
    #pragma unroll
    for (int o = 16; o > 0; o >>= 1) q4 += __shfl_xor(q4, o, 64);
    float rstd = rsqrtf(q4 * (1.f / HID) + 1e-5f);
    if (side == 0) {
        const float4 gv  = *reinterpret_cast<const float4*>(g + c);
        const float4 bev = *reinterpret_cast<const float4*>(be + c);
        float yx = dx * rstd * gv.x + bev.x;
        float yy = dy * rstd * gv.y + bev.y;
        float yz = dz * rstd * gv.z + bev.z;
        float yw = dw * rstd * gv.w + bev.w;
        yx = (yx > 0.f) ? yx : (__expf(yx) - 1.f);
        yy = (yy > 0.f) ? yy : (__expf(yy) - 1.f);
        yz = (yz > 0.f) ? yz : (__expf(yz) - 1.f);
        yw = (yw > 0.f) ? yw : (__expf(yw) - 1.f);
        const float4 rv = *reinterpret_cast<const float4*>(hin + (size_t)n * HID + c);
        *reinterpret_cast<float4*>(hout + (size_t)n * HID + c) =
            make_float4(yx + rv.x, yy + rv.y, yz + rv.z, yw + rv.w);
    }
}

// ---------------- gate[n] = relu(h@gW1+gb1)@gW2 + gb2, tiled 16 nodes/block ----------------
__global__ void k_gate(const float* __restrict__ h, const float* __restrict__ gW1,
                       const float* __restrict__ gb1, const float* __restrict__ gW2,
                       const float* __restrict__ gb2, float* __restrict__ gate) {
    __shared__ float hs[16][HID];
    int tid = threadIdx.x;             // 256
    int base = blockIdx.x * 16;
    for (int idx = tid; idx < 16 * HID; idx += 256) {
        int nn = idx >> 7, k = idx & 127;
        hs[nn][k] = h[(size_t)(base + nn) * HID + k];
    }
    __syncthreads();
    int c = tid & 63;
    int wave = tid >> 6;
    float acc[4] = {0.f, 0.f, 0.f, 0.f};
    #pragma unroll 8
    for (int k = 0; k < HID; k++) {
        float wv = gW1[k * 64 + c];
        #pragma unroll
        for (int q = 0; q < 4; q++) acc[q] += hs[wave * 4 + q][k] * wv;
    }
    float b1 = gb1[c], w2 = gW2[c];
    float p[4];
    #pragma unroll
    for (int q = 0; q < 4; q++) p[q] = fmaxf(acc[q] + b1, 0.f) * w2;
    #pragma unroll
    for (int o = 32; o > 0; o >>= 1) {
        #pragma unroll
        for (int q = 0; q < 4; q++) p[q] += __shfl_xor(p[q], o, 64);
    }
    if (c == 0) {
        float b2 = gb2[0];
        #pragma unroll
        for (int q = 0; q < 4; q++) gate[base + wave * 4 + q] = p[q] + b2;
    }
}

// ---------------- graph boundaries from sorted batch ----------------
__global__ void k_bounds(const int* __restrict__ batch, int* __restrict__ goff) {
    int n = blockIdx.x * blockDim.x + threadIdx.x;
    if (n >= N_NODES) return;
    int cur = batch[n];
    int prev = (n == 0) ? -1 : batch[n - 1];
    for (int g = prev + 1; g <= cur; g++) goff[g] = n;
    if (n == N_NODES - 1) {
        for (int g = cur + 1; g <= NB; g++) goff[g] = N_NODES;
    }
}

__global__ void k_gmaxden(const float* __restrict__ gate, const int* __restrict__ goff,
                          float* __restrict__ gmax, float* __restrict__ gden) {
    int b = blockIdx.x;
    int t = threadIdx.x;               // 256
    __shared__ float red[256];
    int s = goff[b], e = goff[b + 1];
    float m = -__builtin_inff();
    for (int n = s + t; n < e; n += 256) m = fmaxf(m, gate[n]);
    red[t] = m;
    __syncthreads();
    for (int o = 128; o > 0; o >>= 1) { if (t < o) red[t] = fmaxf(red[t], red[t + o]); __syncthreads(); }
    m = red[0];
    __syncthreads();
    float d = 0.f;
    for (int n = s + t; n < e; n += 256) d += __expf(gate[n] - m);
    red[t] = d;
    __syncthreads();
    for (int o = 128; o > 0; o >>= 1) { if (t < o) red[t] += red[t + o]; __syncthreads(); }
    if (t == 0) { gmax[b] = m; gden[b] = red[0]; }
}

__global__ void k_pool(const float* __restrict__ h, const float* __restrict__ gate,
                       const float* __restrict__ gmax, const float* __restrict__ gden,
                       const int* __restrict__ goff, float* __restrict__ pooled) {
    int b = blockIdx.x;
    int part = blockIdx.y;
    int c = threadIdx.x;               // 128
    int s = goff[b], e = goff[b + 1];
    float m = gmax[b];
    float dinv = 1.f / (gden[b] + 1e-16f);
    float acc = 0.f;
    for (int n = s + part; n < e; n += POOL_SPLIT) {
        float att = __expf(gate[n] - m) * dinv;
        acc += att * h[(size_t)n * HID + c];
    }
    atomicAdd(&pooled[b * HID + c], acc);
}

__global__ void k_head(const float* __restrict__ pooled, const float* __restrict__ cW1,
                       const float* __restrict__ cb1, const float* __restrict__ cW2,
                       const float* __restrict__ cb2, float* __restrict__ out) {
    int b = blockIdx.x;
    int t = threadIdx.x;               // 64
    __shared__ float pr[HID];
    __shared__ float tr[64];
    pr[t] = pooled[b * HID + t];
    pr[t + 64] = pooled[b * HID + t + 64];
    __syncthreads();
    float a = cb1[t];
    #pragma unroll 8
    for (int k = 0; k < HID; k++) a += pr[k] * cW1[k * 64 + t];
    tr[t] = fmaxf(a, 0.f);
    __syncthreads();
    if (t < NC) {
        float o = cb2[t];
        #pragma unroll
        for (int k = 0; k < 64; k++) o += tr[k] * cW2[k * NC + t];
        out[b * NC + t] = o;
    }
}

extern "C" void kernel_launch(void* const* d_in, const int* in_sizes, int n_in,
                              void* d_out, int out_size, void* d_ws, size_t ws_size,
                              hipStream_t stream) {
    (void)in_sizes; (void)n_in; (void)out_size; (void)ws_size;
    const float* x     = (const float*)d_in[0];
    const int*   ei    = (const int*)d_in[1];
    const float* ea    = (const float*)d_in[2];
    const int*   batch = (const int*)d_in[3];
    const float* pW    = (const float*)d_in[4];
    const float* pb    = (const float*)d_in[5];
    const float *W[3], *as_[3], *ad_[3], *ae_[3], *We[3], *bb[3], *gg[3], *be[3];
    for (int l = 0; l < 3; l++) {
        int base = 6 + 8 * l;
        W[l]   = (const float*)d_in[base + 0];
        as_[l] = (const float*)d_in[base + 1];
        ad_[l] = (const float*)d_in[base + 2];
        ae_[l] = (const float*)d_in[base + 3];
        We[l]  = (const float*)d_in[base + 4];
        bb[l]  = (const float*)d_in[base + 5];
        gg[l]  = (const float*)d_in[base + 6];
        be[l]  = (const float*)d_in[base + 7];
    }
    const float* gW1 = (const float*)d_in[30];
    const float* gb1 = (const float*)d_in[31];
    const float* gW2 = (const float*)d_in[32];
    const float* gb2 = (const float*)d_in[33];
    const float* cW1 = (const float*)d_in[34];
    const float* cb1 = (const float*)d_in[35];
    const float* cW2 = (const float*)d_in[36];
    const float* cb2 = (const float*)d_in[37];
    float* out = (float*)d_out;

    char* p = (char*)d_ws;
    auto take = [&](size_t bytes) -> char* {
        char* r = p;
        p += (bytes + 255) & ~(size_t)255;
        return r;
    };
    float*  h0      = (float*)take((size_t)N_NODES * HID * 4);
    float*  h1      = (float*)take((size_t)N_NODES * HID * 4);
    __half* xp      = (__half*)take((size_t)N_NODES * HID * 2);
    float*  al_src  = (float*)take((size_t)N_NODES * 4 * 4);
    float*  al_dst  = (float*)take((size_t)N_NODES * 4 * 4);
    float*  w_csr   = (float*)take((size_t)N_EDGES * 4 * 4);
    float4* rec     = (float4*)take((size_t)N_EDGES * 64);
    int*    deg     = (int*)take((size_t)N_NODES * 4);
    int*    offs    = (int*)take((size_t)(N_NODES + 1) * 4);
    int*    pos     = (int*)take((size_t)N_NODES * 4);
    int*    src_csr = (int*)take((size_t)N_EDGES * 4);
    int*    bsum    = (int*)take(256 * 4);
    int*    bpre    = (int*)take(256 * 4);
    float*  WeAe    = (float*)take(ED * 9 * 4);
    float*  gate    = (float*)take((size_t)N_NODES * 4);
    float*  gmax    = (float*)take(NB * 4);
    float*  gden    = (float*)take(NB * 4);
    int*    goff    = (int*)take((NB + 1) * 4);
    float*  pooled  = (float*)take(NB * HID * 4);

    const int* src = ei;
    const int* dst = ei + N_EDGES;

    hipMemsetAsync(deg, 0, (size_t)N_NODES * 4, stream);
    hipMemsetAsync(pooled, 0, (size_t)NB * HID * 4, stream);

    k_proj<<<N_NODES / 16, 256, 0, stream>>>(x, pW, pb, h0);
    k_deg<<<(N_EDGES + 255) / 256, 256, 0, stream>>>(dst, deg);
    k_scanA<<<SCAN_BLOCKS, 256, 0, stream>>>(deg, bsum);
    k_scanB<<<1, 256, 0, stream>>>(bsum, bpre, offs);
    k_scanC<<<SCAN_BLOCKS, 256, 0, stream>>>(deg, bpre, offs, pos);
    k_weae_all<<<1, 256, 0, stream>>>(We[0], ae_[0], We[1], ae_[1], We[2], ae_[2], WeAe);
    k_edge_build<<<(N_EDGES + 255) / 256, 256, 0, stream>>>(src, dst, ea, WeAe, pos, rec);

    float* hc = h0;
    float* hn = h1;
    for (int l = 0; l < 3; l++) {
        if (l < 2) {
            k_node_proj<4><<<N_NODES / 16, 256, 0, stream>>>(hc, W[l], as_[l], ad_[l], xp, al_src, al_dst);
            if (l == 0)
                k_edge_w4<0><<<(N_EDGES + 255) / 256, 256, 0, stream>>>(rec, al_src, al_dst,
                                                                        (float4*)w_csr, src_csr);
            else
                k_edge_w4<1><<<(N_EDGES + 255) / 256, 256, 0, stream>>>(rec, al_src, al_dst,
                                                                        (float4*)w_csr, nullptr);
            k_node_agg<4><<<(N_NODES + 3) / 4, 256, 0, stream>>>(offs, src_csr, w_csr, xp,
                                                                 bb[l], gg[l], be[l], hc, hn);
        } else {
            k_node_proj<1><<<N_NODES / 16, 256, 0, stream>>>(hc, W[l], as_[l], ad_[l], xp, al_src, al_dst);
            k_edge_w1<<<(N_EDGES + 255) / 256, 256, 0, stream>>>(rec, al_src, al_dst, w_csr);
            k_node_agg<1><<<(N_NODES + 3) / 4, 256, 0, stream>>>(offs, src_csr, w_csr, xp,
                                                                 bb[l], gg[l], be[l], hc, hn);
        }
        float* t = hc; hc = hn; hn = t;
    }

    k_gate<<<N_NODES / 16, 256, 0, stream>>>(hc, gW1, gb1, gW2, gb2, gate);
    k_bounds<<<(N_NODES + 255) / 256, 256, 0, stream>>>(batch, goff);
    k_gmaxden<<<NB, 256, 0, stream>>>(gate, goff, gmax, gden);
    k_pool<<<dim3(NB, POOL_SPLIT), HID, 0, stream>>>(hc, gate, gmax, gden, goff, pooled);
    k_head<<<NB, 64, 0, stream>>>(pooled, cW1, cb1, cW2, cb2, out);
}

// Round 6
// 608.362 us; speedup vs baseline: 2.5419x; 1.0413x over previous
//
#include <hip/hip_runtime.h>
#include <hip/hip_fp16.h>
#include <math.h>

#define N_NODES 50000
#define N_EDGES 800000
#define NB      64
#define ND      64
#define ED      16
#define HID     128
#define NC      6
#define POOL_SPLIT 16
#define SCAN_BLOCKS ((N_NODES + 255) / 256)   // 196

// ---------------- h0 = relu(x @ pW + pb), tiled: 16 nodes/block ----------------
__global__ void k_proj(const float* __restrict__ x, const float* __restrict__ pW,
                       const float* __restrict__ pb, float* __restrict__ h) {
    __shared__ float xs[16][ND];
    int tid = threadIdx.x;             // 256
    int base = blockIdx.x * 16;
    for (int idx = tid; idx < 16 * ND; idx += 256) {
        int nn = idx >> 6, k = idx & 63;
        xs[nn][k] = x[(size_t)(base + nn) * ND + k];
    }
    __syncthreads();
    int c = tid & 127;
    int grp = tid >> 7;                // 0,1 -> nodes grp*8..grp*8+7
    float acc[8] = {0.f, 0.f, 0.f, 0.f, 0.f, 0.f, 0.f, 0.f};
    #pragma unroll 4
    for (int k = 0; k < ND; k++) {
        float wv = pW[k * HID + c];
        #pragma unroll
        for (int q = 0; q < 8; q++) acc[q] += xs[grp * 8 + q][k] * wv;
    }
    float bv = pb[c];
    #pragma unroll
    for (int q = 0; q < 8; q++)
        h[(size_t)(base + grp * 8 + q) * HID + c] = fmaxf(acc[q] + bv, 0.f);
}

// ---------------- degree + per-edge rank (atomic lives here, once) ----------------
__global__ void k_deg(const int* __restrict__ dst, int* __restrict__ deg,
                      int* __restrict__ rank) {
    int e = blockIdx.x * blockDim.x + threadIdx.x;
    if (e < N_EDGES) rank[e] = atomicAdd(&deg[dst[e]], 1);
}

__global__ void k_scanA(const int* __restrict__ deg, int* __restrict__ bsum) {
    __shared__ int wsu[4];
    int t = threadIdx.x;
    int i = blockIdx.x * 256 + t;
    int d = (i < N_NODES) ? deg[i] : 0;
    int v = d;
    #pragma unroll
    for (int o = 32; o > 0; o >>= 1) v += __shfl_xor(v, o, 64);
    if ((t & 63) == 0) wsu[t >> 6] = v;
    __syncthreads();
    if (t == 0) bsum[blockIdx.x] = wsu[0] + wsu[1] + wsu[2] + wsu[3];
}

__global__ void k_scanB(const int* __restrict__ bsum, int* __restrict__ bpre,
                        int* __restrict__ offs) {
    __shared__ int sc[256];
    int t = threadIdx.x;
    int d = (t < SCAN_BLOCKS) ? bsum[t] : 0;
    sc[t] = d;
    __syncthreads();
    for (int o = 1; o < 256; o <<= 1) {
        int v = (t >= o) ? sc[t - o] : 0;
        __syncthreads();
        sc[t] += v;
        __syncthreads();
    }
    if (t < SCAN_BLOCKS) bpre[t] = sc[t] - d;
    if (t == 0) offs[N_NODES] = N_EDGES;
}

__global__ void k_scanC(const int* __restrict__ deg, const int* __restrict__ bpre,
                        int* __restrict__ offs) {
    __shared__ int sc[256];
    int t = threadIdx.x;
    int i = blockIdx.x * 256 + t;
    int d = (i < N_NODES) ? deg[i] : 0;
    sc[t] = d;
    __syncthreads();
    for (int o = 1; o < 256; o <<= 1) {
        int v = (t >= o) ? sc[t - o] : 0;
        __syncthreads();
        sc[t] += v;
        __syncthreads();
    }
    if (i < N_NODES) offs[i] = bpre[blockIdx.x] + sc[t] - d;
}

// ---------------- WeAe for all 3 layers: [16][9] (4+4+1) ----------------
__global__ void k_weae_all(const float* __restrict__ We0, const float* __restrict__ ae0,
                           const float* __restrict__ We1, const float* __restrict__ ae1,
                           const float* __restrict__ We2, const float* __restrict__ ae2,
                           float* __restrict__ WeAe) {
    int t = threadIdx.x;
    if (t < 64) {
        int k = t >> 2, h = t & 3;
        float s = 0.f;
        for (int c = 0; c < 32; c++) s += We0[k * HID + h * 32 + c] * ae0[h * 32 + c];
        WeAe[k * 9 + h] = s;
    } else if (t < 128) {
        int tt = t - 64;
        int k = tt >> 2, h = tt & 3;
        float s = 0.f;
        for (int c = 0; c < 32; c++) s += We1[k * HID + h * 32 + c] * ae1[h * 32 + c];
        WeAe[k * 9 + 4 + h] = s;
    } else if (t < 144) {
        int k = t - 128;
        float s = 0.f;
        for (int c = 0; c < HID; c++) s += We2[k * HID + c] * ae2[c];
        WeAe[k * 9 + 8] = s;
    }
}

// ---------------- build packed CSR records: atomic-free, LDS-staged full-line scatter ----------------
// rec[p] (4 x float4): q0={r0..r3}(L0) q1={r4..r7}(L1) q2={r8, src, dst, 0} q3=0
__global__ void k_edge_build(const int* __restrict__ src, const int* __restrict__ dst,
                             const int* __restrict__ rank, const int* __restrict__ offs,
                             const float* __restrict__ ea, const float* __restrict__ WeAe,
                             float4* __restrict__ rec) {
    __shared__ float w[ED * 9];
    __shared__ float4 rs[256][4];      // 16 KB staged records
    __shared__ int rp[256];
    int tid = threadIdx.x;
    if (tid < ED * 9) w[tid] = WeAe[tid];
    __syncthreads();
    int e = blockIdx.x * 256 + tid;
    if (e < N_EDGES) {
        float ev[ED];
        const float4* ep4 = reinterpret_cast<const float4*>(ea + (size_t)e * ED);
        #pragma unroll
        for (int q = 0; q < 4; q++) {
            float4 v = ep4[q];
            ev[q * 4 + 0] = v.x; ev[q * 4 + 1] = v.y;
            ev[q * 4 + 2] = v.z; ev[q * 4 + 3] = v.w;
        }
        float r[9];
        #pragma unroll
        for (int j = 0; j < 9; j++) r[j] = 0.f;
        #pragma unroll
        for (int k = 0; k < ED; k++) {
            float evk = ev[k];
            #pragma unroll
            for (int j = 0; j < 9; j++) r[j] += evk * w[k * 9 + j];
        }
        int d = dst[e], s = src[e];
        rp[tid] = offs[d] + rank[e];
        rs[tid][0] = make_float4(r[0], r[1], r[2], r[3]);
        rs[tid][1] = make_float4(r[4], r[5], r[6], r[7]);
        rs[tid][2] = make_float4(r[8], __int_as_float(s), __int_as_float(d), 0.f);
        rs[tid][3] = make_float4(0.f, 0.f, 0.f, 0.f);
    } else {
        rp[tid] = -1;
    }
    __syncthreads();
    // cooperative write: 4 lanes emit one record's 4 quads -> one full 64B line
    int g0 = tid >> 2, q = tid & 3;
    #pragma unroll
    for (int rr = 0; rr < 4; rr++) {
        int g = rr * 64 + g0;
        int p = rp[g];
        if (p >= 0) rec[(size_t)p * 4 + q] = rs[g][q];
    }
}

// ---------------- per-layer: xp(fp16) = h@W, al_src/al_dst; tiled 16 nodes/block ----------------
template <int H>
__global__ void k_node_proj(const float* __restrict__ h, const float* __restrict__ W,
                            const float* __restrict__ as_, const float* __restrict__ ad_,
                            __half* __restrict__ xp, float* __restrict__ al_src,
                            float* __restrict__ al_dst) {
    __shared__ float hs[16][HID];
    __shared__ float red_s[4][8];
    __shared__ float red_d[4][8];
    int tid = threadIdx.x;             // 256
    int base = blockIdx.x * 16;
    for (int idx = tid; idx < 16 * HID; idx += 256) {
        int nn = idx >> 7, k = idx & 127;
        hs[nn][k] = h[(size_t)(base + nn) * HID + k];
    }
    __syncthreads();
    int c = tid & 127;
    int grp = tid >> 7;                // 0,1 -> nodes grp*8..grp*8+7
    float acc[8] = {0.f, 0.f, 0.f, 0.f, 0.f, 0.f, 0.f, 0.f};
    #pragma unroll 4
    for (int k = 0; k < HID; k++) {
        float wv = W[k * HID + c];
        #pragma unroll
        for (int q = 0; q < 8; q++) acc[q] += hs[grp * 8 + q][k] * wv;
    }
    #pragma unroll
    for (int q = 0; q < 8; q++)
        xp[(size_t)(base + grp * 8 + q) * HID + c] = __float2half_rn(acc[q]);
    float av = as_[c], dv = ad_[c];
    float rs[8], rd[8];
    #pragma unroll
    for (int q = 0; q < 8; q++) { rs[q] = acc[q] * av; rd[q] = acc[q] * dv; }
    if (H == 4) {
        #pragma unroll
        for (int o = 16; o > 0; o >>= 1) {
            #pragma unroll
            for (int q = 0; q < 8; q++) {
                rs[q] += __shfl_xor(rs[q], o, 64);
                rd[q] += __shfl_xor(rd[q], o, 64);
            }
        }
        if ((c & 31) == 0) {
            int head = c >> 5;
            #pragma unroll
            for (int q = 0; q < 8; q++) {
                int n = base + grp * 8 + q;
                al_src[n * 4 + head] = rs[q];
                al_dst[n * 4 + head] = rd[q];
            }
        }
    } else {
        #pragma unroll
        for (int o = 32; o > 0; o >>= 1) {
            #pragma unroll
            for (int q = 0; q < 8; q++) {
                rs[q] += __shfl_xor(rs[q], o, 64);
                rd[q] += __shfl_xor(rd[q], o, 64);
            }
        }
        int wave = tid >> 6;
        if ((tid & 63) == 0) {
            #pragma unroll
            for (int q = 0; q < 8; q++) { red_s[wave][q] = rs[q]; red_d[wave][q] = rd[q]; }
        }
        __syncthreads();
        if (tid < 16) {
            int gg = tid >> 3, q = tid & 7;
            int n = base + gg * 8 + q;
            al_src[n] = red_s[gg * 2][q] + red_s[gg * 2 + 1][q];
            al_dst[n] = red_d[gg * 2][q] + red_d[gg * 2 + 1][q];
        }
    }
}

// ---------------- per-layer edge weights from packed records ----------------
template <int SLOT>    // 0 or 1 (H=4 layers)
__global__ void k_edge_w4(const float4* __restrict__ rec, const float* __restrict__ al_src,
                          const float* __restrict__ al_dst, float4* __restrict__ w_csr,
                          int* __restrict__ src_out) {
    int i = blockIdx.x * blockDim.x + threadIdx.x;
    if (i >= N_EDGES) return;
    float4 r    = rec[(size_t)i * 4 + SLOT];
    float4 meta = rec[(size_t)i * 4 + 2];
    int s = __float_as_int(meta.y);
    int d = __float_as_int(meta.z);
    float4 sa = *reinterpret_cast<const float4*>(al_src + (size_t)s * 4);
    float4 da = *reinterpret_cast<const float4*>(al_dst + (size_t)d * 4);
    float4 wv;
    float al;
    al = sa.x + da.x + r.x; al = (al >= 0.f) ? al : 0.2f * al; wv.x = __expf(al);
    al = sa.y + da.y + r.y; al = (al >= 0.f) ? al : 0.2f * al; wv.y = __expf(al);
    al = sa.z + da.z + r.z; al = (al >= 0.f) ? al : 0.2f * al; wv.z = __expf(al);
    al = sa.w + da.w + r.w; al = (al >= 0.f) ? al : 0.2f * al; wv.w = __expf(al);
    w_csr[i] = wv;
    if (SLOT == 0) src_out[i] = s;
}

__global__ void k_edge_w1(const float4* __restrict__ rec, const float* __restrict__ al_src,
                          const float* __restrict__ al_dst, float* __restrict__ w_csr) {
    int i = blockIdx.x * blockDim.x + threadIdx.x;
    if (i >= N_EDGES) return;
    float4 meta = rec[(size_t)i * 4 + 2];
    int s = __float_as_int(meta.y);
    int d = __float_as_int(meta.z);
    float al = al_src[s] + al_dst[d] + meta.x;
    al = (al >= 0.f) ? al : 0.2f * al;
    w_csr[i] = __expf(al);
}

// ---------------- fused gather: 8 edges/wave in flight (4 per side), fp16 xp ----------------
template <int H>
__global__ void k_node_agg(const int* __restrict__ offs, const int* __restrict__ src_csr,
                           const float* __restrict__ w_csr, const __half* __restrict__ xp,
                           const float* __restrict__ bias, const float* __restrict__ g,
                           const float* __restrict__ be, const float* __restrict__ hin,
                           float* __restrict__ hout) {
    const int C = HID / H;
    int tid = threadIdx.x;             // 256 -> 4 waves
    int wave = tid >> 6;
    int lane = tid & 63;
    int n = blockIdx.x * 4 + wave;
    if (n >= N_NODES) return;
    int e0 = offs[n], e1 = offs[n + 1];
    int side = lane >> 5;
    int hl = lane & 31;
    int c = hl * 4;
    const int h = c / C;
    float ax = 0.f, ay = 0.f, az = 0.f, aw = 0.f, den = 0.f;

    auto ld = [&](int idx, int& s, float& w) {
        if (idx < e1) {
            s = src_csr[idx];
            w = (H == 4) ? w_csr[(size_t)idx * 4 + h] : w_csr[idx];
        } else { s = 0; w = 0.f; }
    };
    auto acc1 = [&](uint2 r, float w) {
        union { uint2 u; __half2 h2[2]; } t; t.u = r;
        float2 lo = __half22float2(t.h2[0]), hi = __half22float2(t.h2[1]);
        ax += w * lo.x; ay += w * lo.y; az += w * hi.x; aw += w * hi.y; den += w;
    };

    int i = e0 + side;                 // this side: i, i+2, i+4, ... ; 4 in flight, step 8
    int sA, sB, sC, sD; float wA, wB, wC, wD;
    ld(i, sA, wA); ld(i + 2, sB, wB); ld(i + 4, sC, wC); ld(i + 6, sD, wD);
    while (i < e1) {
        uint2 rA = *reinterpret_cast<const uint2*>(xp + (size_t)sA * HID + c);
        uint2 rB = *reinterpret_cast<const uint2*>(xp + (size_t)sB * HID + c);
        uint2 rC = *reinterpret_cast<const uint2*>(xp + (size_t)sC * HID + c);
        uint2 rD = *reinterpret_cast<const uint2*>(xp + (size_t)sD * HID + c);
        int ni = i + 8;
        int tA, tB, tC, tD; float vA, vB, vC, vD;
        ld(ni, tA, vA); ld(ni + 2, tB, vB); ld(ni + 4, tC, vC); ld(ni + 6, tD, vD);
        acc1(rA, wA); acc1(rB, wB); acc1(rC, wC); acc1(rD, wD);
        sA = tA; wA = vA; sB = tB; wB = vB; sC = tC; wC = vC; sD = tD; wD = vD;
        i = ni;
    }
    // combine sides (same channels)
    ax += __shfl_xor(ax, 32, 64);
    ay += __shfl_xor(ay, 32, 64);
    az += __shfl_xor(az, 32, 64);
    aw += __shfl_xor(aw, 32, 64);
    den += __shfl_xor(den, 32, 64);

    float inv = 1.f / (den + 1e-16f);
    const float4 bv = *reinterpret_cast<const float4*>(bias + c);
    float vx = ax * inv + bv.x, vy = ay * inv + bv.y;
    float vz = az * inv + bv.z, vw = aw * inv + bv.w;
    float s4 = vx + vy + vz + vw;
    #pragma unroll
    for (int o = 16; o > 0; o >>= 1) s4 += __shfl_xor(s4, o, 64);
    float mean = s4 * (1.f / HID);
    float dx = vx - mean, dy = vy - mean, dz = vz - mean, dw = vw - mean;
    float q4 = dx * dx + dy * dy + dz * dz + dw * dw;
    #pragma unroll
    for (int o = 16; o > 0; o >>= 1) q4 += __shfl_xor(q4, o, 64);
    float rstd = rsqrtf(q4 * (1.f / HID) + 1e-5f);
    if (side == 0) {
        const float4 gv  = *reinterpret_cast<const float4*>(g + c);
        const float4 bev = *reinterpret_cast<const float4*>(be + c);
        float yx = dx * rstd * gv.x + bev.x;
        float yy = dy * rstd * gv.y + bev.y;
        float yz = dz * rstd * gv.z + bev.z;
        float yw = dw * rstd * gv.w + bev.w;
        yx = (yx > 0.f) ? yx : (__expf(yx) - 1.f);
        yy = (yy > 0.f) ? yy : (__expf(yy) - 1.f);
        yz = (yz > 0.f) ? yz : (__expf(yz) - 1.f);
        yw = (yw > 0.f) ? yw : (__expf(yw) - 1.f);
        const float4 rv = *reinterpret_cast<const float4*>(hin + (size_t)n * HID + c);
        *reinterpret_cast<float4*>(hout + (size_t)n * HID + c) =
            make_float4(yx + rv.x, yy + rv.y, yz + rv.z, yw + rv.w);
    }
}

// ---------------- gate[n] = relu(h@gW1+gb1)@gW2 + gb2, tiled 16 nodes/block ----------------
__global__ void k_gate(const float* __restrict__ h, const float* __restrict__ gW1,
                       const float* __restrict__ gb1, const float* __restrict__ gW2,
                       const float* __restrict__ gb2, float* __restrict__ gate) {
    __shared__ float hs[16][HID];
    int tid = threadIdx.x;             // 256
    int base = blockIdx.x * 16;
    for (int idx = tid; idx < 16 * HID; idx += 256) {
        int nn = idx >> 7, k = idx & 127;
        hs[nn][k] = h[(size_t)(base + nn) * HID + k];
    }
    __syncthreads();
    int c = tid & 63;
    int wave = tid >> 6;
    float acc[4] = {0.f, 0.f, 0.f, 0.f};
    #pragma unroll 8
    for (int k = 0; k < HID; k++) {
        float wv = gW1[k * 64 + c];
        #pragma unroll
        for (int q = 0; q < 4; q++) acc[q] += hs[wave * 4 + q][k] * wv;
    }
    float b1 = gb1[c], w2 = gW2[c];
    float p[4];
    #pragma unroll
    for (int q = 0; q < 4; q++) p[q] = fmaxf(acc[q] + b1, 0.f) * w2;
    #pragma unroll
    for (int o = 32; o > 0; o >>= 1) {
        #pragma unroll
        for (int q = 0; q < 4; q++) p[q] += __shfl_xor(p[q], o, 64);
    }
    if (c == 0) {
        float b2 = gb2[0];
        #pragma unroll
        for (int q = 0; q < 4; q++) gate[base + wave * 4 + q] = p[q] + b2;
    }
}

// ---------------- graph boundaries from sorted batch ----------------
__global__ void k_bounds(const int* __restrict__ batch, int* __restrict__ goff) {
    int n = blockIdx.x * blockDim.x + threadIdx.x;
    if (n >= N_NODES) return;
    int cur = batch[n];
    int prev = (n == 0) ? -1 : batch[n - 1];
    for (int g = prev + 1; g <= cur; g++) goff[g] = n;
    if (n == N_NODES - 1) {
        for (int g = cur + 1; g <= NB; g++) goff[g] = N_NODES;
    }
}

__global__ void k_gmaxden(const float* __restrict__ gate, const int* __restrict__ goff,
                          float* __restrict__ gmax, float* __restrict__ gden) {
    int b = blockIdx.x;
    int t = threadIdx.x;               // 256
    __shared__ float red[256];
    int s = goff[b], e = goff[b + 1];
    float m = -__builtin_inff();
    for (int n = s + t; n < e; n += 256) m = fmaxf(m, gate[n]);
    red[t] = m;
    __syncthreads();
    for (int o = 128; o > 0; o >>= 1) { if (t < o) red[t] = fmaxf(red[t], red[t + o]); __syncthreads(); }
    m = red[0];
    __syncthreads();
    float d = 0.f;
    for (int n = s + t; n < e; n += 256) d += __expf(gate[n] - m);
    red[t] = d;
    __syncthreads();
    for (int o = 128; o > 0; o >>= 1) { if (t < o) red[t] += red[t + o]; __syncthreads(); }
    if (t == 0) { gmax[b] = m; gden[b] = red[0]; }
}

__global__ void k_pool(const float* __restrict__ h, const float* __restrict__ gate,
                       const float* __restrict__ gmax, const float* __restrict__ gden,
                       const int* __restrict__ goff, float* __restrict__ pooled) {
    int b = blockIdx.x;
    int part = blockIdx.y;
    int c = threadIdx.x;               // 128
    int s = goff[b], e = goff[b + 1];
    float m = gmax[b];
    float dinv = 1.f / (gden[b] + 1e-16f);
    float acc = 0.f;
    for (int n = s + part; n < e; n += POOL_SPLIT) {
        float att = __expf(gate[n] - m) * dinv;
        acc += att * h[(size_t)n * HID + c];
    }
    atomicAdd(&pooled[b * HID + c], acc);
}

__global__ void k_head(const float* __restrict__ pooled, const float* __restrict__ cW1,
                       const float* __restrict__ cb1, const float* __restrict__ cW2,
                       const float* __restrict__ cb2, float* __restrict__ out) {
    int b = blockIdx.x;
    int t = threadIdx.x;               // 64
    __shared__ float pr[HID];
    __shared__ float tr[64];
    pr[t] = pooled[b * HID + t];
    pr[t + 64] = pooled[b * HID + t + 64];
    __syncthreads();
    float a = cb1[t];
    #pragma unroll 8
    for (int k = 0; k < HID; k++) a += pr[k] * cW1[k * 64 + t];
    tr[t] = fmaxf(a, 0.f);
    __syncthreads();
    if (t < NC) {
        float o = cb2[t];
        #pragma unroll
        for (int k = 0; k < 64; k++) o += tr[k] * cW2[k * NC + t];
        out[b * NC + t] = o;
    }
}

extern "C" void kernel_launch(void* const* d_in, const int* in_sizes, int n_in,
                              void* d_out, int out_size, void* d_ws, size_t ws_size,
                              hipStream_t stream) {
    (void)in_sizes; (void)n_in; (void)out_size; (void)ws_size;
    const float* x     = (const float*)d_in[0];
    const int*   ei    = (const int*)d_in[1];
    const float* ea    = (const float*)d_in[2];
    const int*   batch = (const int*)d_in[3];
    const float* pW    = (const float*)d_in[4];
    const float* pb    = (const float*)d_in[5];
    const float *W[3], *as_[3], *ad_[3], *ae_[3], *We[3], *bb[3], *gg[3], *be[3];
    for (int l = 0; l < 3; l++) {
        int base = 6 + 8 * l;
        W[l]   = (const float*)d_in[base + 0];
        as_[l] = (const float*)d_in[base + 1];
        ad_[l] = (const float*)d_in[base + 2];
        ae_[l] = (const float*)d_in[base + 3];
        We[l]  = (const float*)d_in[base + 4];
        bb[l]  = (const float*)d_in[base + 5];
        gg[l]  = (const float*)d_in[base + 6];
        be[l]  = (const float*)d_in[base + 7];
    }
    const float* gW1 = (const float*)d_in[30];
    const float* gb1 = (const float*)d_in[31];
    const float* gW2 = (const float*)d_in[32];
    const float* gb2 = (const float*)d_in[33];
    const float* cW1 = (const float*)d_in[34];
    const float* cb1 = (const float*)d_in[35];
    const float* cW2 = (const float*)d_in[36];
    const float* cb2 = (const float*)d_in[37];
    float* out = (float*)d_out;

    char* p = (char*)d_ws;
    auto take = [&](size_t bytes) -> char* {
        char* r = p;
        p += (bytes + 255) & ~(size_t)255;
        return r;
    };
    float*  h0      = (float*)take((size_t)N_NODES * HID * 4);
    float*  h1      = (float*)take((size_t)N_NODES * HID * 4);
    __half* xp      = (__half*)take((size_t)N_NODES * HID * 2);
    float*  al_src  = (float*)take((size_t)N_NODES * 4 * 4);
    float*  al_dst  = (float*)take((size_t)N_NODES * 4 * 4);
    float*  w_csr   = (float*)take((size_t)N_EDGES * 4 * 4);
    float4* rec     = (float4*)take((size_t)N_EDGES * 64);
    int*    deg     = (int*)take((size_t)N_NODES * 4);
    int*    offs    = (int*)take((size_t)(N_NODES + 1) * 4);
    int*    rank    = (int*)take((size_t)N_EDGES * 4);
    int*    src_csr = (int*)take((size_t)N_EDGES * 4);
    int*    bsum    = (int*)take(256 * 4);
    int*    bpre    = (int*)take(256 * 4);
    float*  WeAe    = (float*)take(ED * 9 * 4);
    float*  gate    = (float*)take((size_t)N_NODES * 4);
    float*  gmax    = (float*)take(NB * 4);
    float*  gden    = (float*)take(NB * 4);
    int*    goff    = (int*)take((NB + 1) * 4);
    float*  pooled  = (float*)take(NB * HID * 4);

    const int* src = ei;
    const int* dst = ei + N_EDGES;

    hipMemsetAsync(deg, 0, (size_t)N_NODES * 4, stream);
    hipMemsetAsync(pooled, 0, (size_t)NB * HID * 4, stream);

    k_proj<<<N_NODES / 16, 256, 0, stream>>>(x, pW, pb, h0);
    k_deg<<<(N_EDGES + 255) / 256, 256, 0, stream>>>(dst, deg, rank);
    k_scanA<<<SCAN_BLOCKS, 256, 0, stream>>>(deg, bsum);
    k_scanB<<<1, 256, 0, stream>>>(bsum, bpre, offs);
    k_scanC<<<SCAN_BLOCKS, 256, 0, stream>>>(deg, bpre, offs);
    k_weae_all<<<1, 256, 0, stream>>>(We[0], ae_[0], We[1], ae_[1], We[2], ae_[2], WeAe);
    k_edge_build<<<(N_EDGES + 255) / 256, 256, 0, stream>>>(src, dst, rank, offs, ea, WeAe, rec);

    float* hc = h0;
    float* hn = h1;
    for (int l = 0; l < 3; l++) {
        if (l < 2) {
            k_node_proj<4><<<N_NODES / 16, 256, 0, stream>>>(hc, W[l], as_[l], ad_[l], xp, al_src, al_dst);
            if (l == 0)
                k_edge_w4<0><<<(N_EDGES + 255) / 256, 256, 0, stream>>>(rec, al_src, al_dst,
                                                                        (float4*)w_csr, src_csr);
            else
                k_edge_w4<1><<<(N_EDGES + 255) / 256, 256, 0, stream>>>(rec, al_src, al_dst,
                                                                        (float4*)w_csr, nullptr);
            k_node_agg<4><<<(N_NODES + 3) / 4, 256, 0, stream>>>(offs, src_csr, w_csr, xp,
                                                                 bb[l], gg[l], be[l], hc, hn);
        } else {
            k_node_proj<1><<<N_NODES / 16, 256, 0, stream>>>(hc, W[l], as_[l], ad_[l], xp, al_src, al_dst);
            k_edge_w1<<<(N_EDGES + 255) / 256, 256, 0, stream>>>(rec, al_src, al_dst, w_csr);
            k_node_agg<1><<<(N_NODES + 3) / 4, 256, 0, stream>>>(offs, src_csr, w_csr, xp,
                                                                 bb[l], gg[l], be[l], hc, hn);
        }
        float* t = hc; hc = hn; hn = t;
    }

    k_gate<<<N_NODES / 16, 256, 0, stream>>>(hc, gW1, gb1, gW2, gb2, gate);
    k_bounds<<<(N_NODES + 255) / 256, 256, 0, stream>>>(batch, goff);
    k_gmaxden<<<NB, 256, 0, stream>>>(gate, goff, gmax, gden);
    k_pool<<<dim3(NB, POOL_SPLIT), HID, 0, stream>>>(hc, gate, gmax, gden, goff, pooled);
    k_head<<<NB, 64, 0, stream>>>(pooled, cW1, cb1, cW2, cb2, out);
}

// Round 7
// 511.320 us; speedup vs baseline: 3.0244x; 1.1898x over previous
//
#include <hip/hip_runtime.h>
#include <hip/hip_fp16.h>
#include <math.h>

#define N_NODES 50000
#define N_EDGES 800000
#define NB      64
#define ND      64
#define ED      16
#define HID     128
#define NC      6
#define POOL_SPLIT 16
#define SCAN_BLOCKS ((N_NODES + 255) / 256)   // 196
#define GEMM_BLOCKS ((N_NODES + 63) / 64)     // 782

typedef _Float16 f16;
typedef f16  half8  __attribute__((ext_vector_type(8)));
typedef float floatx4 __attribute__((ext_vector_type(4)));

// ---------------- one-time: transpose weights to fp16 Wt[n][k] ----------------
__global__ void k_wcvt(const float* __restrict__ pW, const float* __restrict__ W0,
                       const float* __restrict__ W1, const float* __restrict__ W2,
                       f16* __restrict__ Wtp, f16* __restrict__ Wt0,
                       f16* __restrict__ Wt1, f16* __restrict__ Wt2) {
    int i = blockIdx.x * 256 + threadIdx.x;
    if (i < 128 * 64) {                 // pW: [64][128] -> Wtp[n][k], K=64
        int n = i / 64, k = i % 64;
        Wtp[i] = (f16)pW[k * 128 + n];
    }
    if (i < 128 * 128) {                // W: [128][128] -> Wt[n][k]
        int n = i / 128, k = i % 128;
        Wt0[i] = (f16)W0[k * 128 + n];
        Wt1[i] = (f16)W1[k * 128 + n];
        Wt2[i] = (f16)W2[k * 128 + n];
    }
}

// ---------------- MFMA GEMM: out = act[M,K] @ W[K,128] ----------------
// MODE 0: h = relu(out + bias) fp32    (proj, K=64)
// MODE 1: xp fp16 + al_src/al_dst per head (H=4, head w = cols 32w..32w+31)
// MODE 2: xp fp16 + al_src/al_dst (H=1)
template <int K, int MODE>
__global__ __launch_bounds__(256) void k_gemm(
        const float* __restrict__ act, const f16* __restrict__ Wt,
        const float* __restrict__ bias, const float* __restrict__ as_,
        const float* __restrict__ ad_, float* __restrict__ hout,
        __half* __restrict__ xp, float* __restrict__ al_src,
        float* __restrict__ al_dst) {
    constexpr int KP = K + 8;           // +8 halves pad: breaks 16-way LDS conflict
    __shared__ __align__(16) f16 A[64 * KP];
    __shared__ float part_s[4][64];
    __shared__ float part_d[4][64];
    int tid = threadIdx.x;
    int base = blockIdx.x * 64;

    // stage act -> fp16 LDS (coalesced float4 loads)
    constexpr int NV = 64 * K / 4 / 256;
    #pragma unroll
    for (int i = 0; i < NV; i++) {
        int v = tid + i * 256;
        int row = v / (K / 4);
        int k4 = v % (K / 4);
        float4 xv = make_float4(0.f, 0.f, 0.f, 0.f);
        if (base + row < N_NODES)
            xv = *(const float4*)(act + (size_t)(base + row) * K + k4 * 4);
        f16* dp = &A[row * KP + k4 * 4];
        dp[0] = (f16)xv.x; dp[1] = (f16)xv.y; dp[2] = (f16)xv.z; dp[3] = (f16)xv.w;
    }
    __syncthreads();

    int w = tid >> 6, l = tid & 63;
    int lm = l & 15, q = l >> 4;
    floatx4 acc[4][2];
    #pragma unroll
    for (int mt = 0; mt < 4; mt++)
        #pragma unroll
        for (int j = 0; j < 2; j++)
            acc[mt][j] = (floatx4){0.f, 0.f, 0.f, 0.f};

    #pragma unroll
    for (int kt = 0; kt < K / 32; kt++) {
        int ko = kt * 32 + q * 8;
        half8 b0 = *(const half8*)(Wt + (size_t)(w * 32 + lm) * K + ko);
        half8 b1 = *(const half8*)(Wt + (size_t)(w * 32 + 16 + lm) * K + ko);
        #pragma unroll
        for (int mt = 0; mt < 4; mt++) {
            half8 a = *(const half8*)(&A[(mt * 16 + lm) * KP + ko]);
            acc[mt][0] = __builtin_amdgcn_mfma_f32_16x16x32_f16(a, b0, acc[mt][0], 0, 0, 0);
            acc[mt][1] = __builtin_amdgcn_mfma_f32_16x16x32_f16(a, b1, acc[mt][1], 0, 0, 0);
        }
    }

    if (MODE == 0) {
        float b0 = bias[w * 32 + lm];
        float b1 = bias[w * 32 + 16 + lm];
        #pragma unroll
        for (int mt = 0; mt < 4; mt++)
            #pragma unroll
            for (int r = 0; r < 4; r++) {
                int row = mt * 16 + q * 4 + r;
                if (base + row < N_NODES) {
                    hout[(size_t)(base + row) * HID + w * 32 + lm]      = fmaxf(acc[mt][0][r] + b0, 0.f);
                    hout[(size_t)(base + row) * HID + w * 32 + 16 + lm] = fmaxf(acc[mt][1][r] + b1, 0.f);
                }
            }
    } else {
        float a0 = as_[w * 32 + lm], a1 = as_[w * 32 + 16 + lm];
        float e0 = ad_[w * 32 + lm], e1 = ad_[w * 32 + 16 + lm];
        float ps[4][4], pd[4][4];
        #pragma unroll
        for (int mt = 0; mt < 4; mt++)
            #pragma unroll
            for (int r = 0; r < 4; r++) {
                ps[mt][r] = acc[mt][0][r] * a0 + acc[mt][1][r] * a1;
                pd[mt][r] = acc[mt][0][r] * e0 + acc[mt][1][r] * e1;
            }
        #pragma unroll
        for (int off = 1; off < 16; off <<= 1)
            #pragma unroll
            for (int mt = 0; mt < 4; mt++)
                #pragma unroll
                for (int r = 0; r < 4; r++) {
                    ps[mt][r] += __shfl_xor(ps[mt][r], off, 64);
                    pd[mt][r] += __shfl_xor(pd[mt][r], off, 64);
                }
        if (MODE == 1) {
            if (lm == 0)
                #pragma unroll
                for (int mt = 0; mt < 4; mt++)
                    #pragma unroll
                    for (int r = 0; r < 4; r++) {
                        int n = base + mt * 16 + q * 4 + r;
                        if (n < N_NODES) {
                            al_src[n * 4 + w] = ps[mt][r];
                            al_dst[n * 4 + w] = pd[mt][r];
                        }
                    }
        } else {
            if (lm == 0)
                #pragma unroll
                for (int mt = 0; mt < 4; mt++)
                    #pragma unroll
                    for (int r = 0; r < 4; r++) {
                        part_s[w][mt * 16 + q * 4 + r] = ps[mt][r];
                        part_d[w][mt * 16 + q * 4 + r] = pd[mt][r];
                    }
        }
        __syncthreads();                 // A-tile reads done; part writes visible
        // stage xp fp16 into (dead) A buffer, [row][col] stride KP
        #pragma unroll
        for (int mt = 0; mt < 4; mt++)
            #pragma unroll
            for (int r = 0; r < 4; r++) {
                int row = mt * 16 + q * 4 + r;
                A[row * KP + w * 32 + lm]      = (f16)acc[mt][0][r];
                A[row * KP + w * 32 + 16 + lm] = (f16)acc[mt][1][r];
            }
        if (MODE == 2 && tid < 64) {
            int n = base + tid;
            if (n < N_NODES) {
                al_src[n] = part_s[0][tid] + part_s[1][tid] + part_s[2][tid] + part_s[3][tid];
                al_dst[n] = part_d[0][tid] + part_d[1][tid] + part_d[2][tid] + part_d[3][tid];
            }
        }
        __syncthreads();
        #pragma unroll
        for (int i = 0; i < 4; i++) {    // 64 rows x 16 chunks of 8 halves
            int v = tid + i * 256;
            int row = v >> 4, c8 = v & 15;
            if (base + row < N_NODES) {
                float4 hv = *(const float4*)(&A[row * KP + c8 * 8]);
                *reinterpret_cast<float4*>(reinterpret_cast<char*>(xp) +
                    ((size_t)(base + row) * HID + c8 * 8) * 2) = hv;
            }
        }
    }
}

// ---------------- degree + per-edge rank ----------------
__global__ void k_deg(const int* __restrict__ dst, int* __restrict__ deg,
                      int* __restrict__ rank) {
    int e = blockIdx.x * blockDim.x + threadIdx.x;
    if (e < N_EDGES) rank[e] = atomicAdd(&deg[dst[e]], 1);
}

__global__ void k_scanA(const int* __restrict__ deg, int* __restrict__ bsum) {
    __shared__ int wsu[4];
    int t = threadIdx.x;
    int i = blockIdx.x * 256 + t;
    int d = (i < N_NODES) ? deg[i] : 0;
    int v = d;
    #pragma unroll
    for (int o = 32; o > 0; o >>= 1) v += __shfl_xor(v, o, 64);
    if ((t & 63) == 0) wsu[t >> 6] = v;
    __syncthreads();
    if (t == 0) bsum[blockIdx.x] = wsu[0] + wsu[1] + wsu[2] + wsu[3];
}

__global__ void k_scanB(const int* __restrict__ bsum, int* __restrict__ bpre,
                        int* __restrict__ offs) {
    __shared__ int sc[256];
    int t = threadIdx.x;
    int d = (t < SCAN_BLOCKS) ? bsum[t] : 0;
    sc[t] = d;
    __syncthreads();
    for (int o = 1; o < 256; o <<= 1) {
        int v = (t >= o) ? sc[t - o] : 0;
        __syncthreads();
        sc[t] += v;
        __syncthreads();
    }
    if (t < SCAN_BLOCKS) bpre[t] = sc[t] - d;
    if (t == 0) offs[N_NODES] = N_EDGES;
}

__global__ void k_scanC(const int* __restrict__ deg, const int* __restrict__ bpre,
                        int* __restrict__ offs) {
    __shared__ int sc[256];
    int t = threadIdx.x;
    int i = blockIdx.x * 256 + t;
    int d = (i < N_NODES) ? deg[i] : 0;
    sc[t] = d;
    __syncthreads();
    for (int o = 1; o < 256; o <<= 1) {
        int v = (t >= o) ? sc[t - o] : 0;
        __syncthreads();
        sc[t] += v;
        __syncthreads();
    }
    if (i < N_NODES) offs[i] = bpre[blockIdx.x] + sc[t] - d;
}

// ---------------- WeAe for all 3 layers: [16][9] ----------------
__global__ void k_weae_all(const float* __restrict__ We0, const float* __restrict__ ae0,
                           const float* __restrict__ We1, const float* __restrict__ ae1,
                           const float* __restrict__ We2, const float* __restrict__ ae2,
                           float* __restrict__ WeAe) {
    int t = threadIdx.x;
    if (t < 64) {
        int k = t >> 2, h = t & 3;
        float s = 0.f;
        for (int c = 0; c < 32; c++) s += We0[k * HID + h * 32 + c] * ae0[h * 32 + c];
        WeAe[k * 9 + h] = s;
    } else if (t < 128) {
        int tt = t - 64;
        int k = tt >> 2, h = tt & 3;
        float s = 0.f;
        for (int c = 0; c < 32; c++) s += We1[k * HID + h * 32 + c] * ae1[h * 32 + c];
        WeAe[k * 9 + 4 + h] = s;
    } else if (t < 144) {
        int k = t - 128;
        float s = 0.f;
        for (int c = 0; c < HID; c++) s += We2[k * HID + c] * ae2[c];
        WeAe[k * 9 + 8] = s;
    }
}

// ---------------- build packed CSR records (atomic-free, full-line scatter) ----------------
__global__ void k_edge_build(const int* __restrict__ src, const int* __restrict__ dst,
                             const int* __restrict__ rank, const int* __restrict__ offs,
                             const float* __restrict__ ea, const float* __restrict__ WeAe,
                             float4* __restrict__ rec) {
    __shared__ float w[ED * 9];
    __shared__ float4 rs[256][4];
    __shared__ int rp[256];
    int tid = threadIdx.x;
    if (tid < ED * 9) w[tid] = WeAe[tid];
    __syncthreads();
    int e = blockIdx.x * 256 + tid;
    if (e < N_EDGES) {
        float ev[ED];
        const float4* ep4 = reinterpret_cast<const float4*>(ea + (size_t)e * ED);
        #pragma unroll
        for (int q = 0; q < 4; q++) {
            float4 v = ep4[q];
            ev[q * 4 + 0] = v.x; ev[q * 4 + 1] = v.y;
            ev[q * 4 + 2] = v.z; ev[q * 4 + 3] = v.w;
        }
        float r[9];
        #pragma unroll
        for (int j = 0; j < 9; j++) r[j] = 0.f;
        #pragma unroll
        for (int k = 0; k < ED; k++) {
            float evk = ev[k];
            #pragma unroll
            for (int j = 0; j < 9; j++) r[j] += evk * w[k * 9 + j];
        }
        int d = dst[e], s = src[e];
        rp[tid] = offs[d] + rank[e];
        rs[tid][0] = make_float4(r[0], r[1], r[2], r[3]);
        rs[tid][1] = make_float4(r[4], r[5], r[6], r[7]);
        rs[tid][2] = make_float4(r[8], __int_as_float(s), __int_as_float(d), 0.f);
        rs[tid][3] = make_float4(0.f, 0.f, 0.f, 0.f);
    } else {
        rp[tid] = -1;
    }
    __syncthreads();
    int g0 = tid >> 2, q = tid & 3;
    #pragma unroll
    for (int rr = 0; rr < 4; rr++) {
        int g = rr * 64 + g0;
        int p = rp[g];
        if (p >= 0) rec[(size_t)p * 4 + q] = rs[g][q];
    }
}

// ---------------- per-layer edge weights from packed records ----------------
template <int SLOT>
__global__ void k_edge_w4(const float4* __restrict__ rec, const float* __restrict__ al_src,
                          const float* __restrict__ al_dst, float4* __restrict__ w_csr,
                          int* __restrict__ src_out) {
    int i = blockIdx.x * blockDim.x + threadIdx.x;
    if (i >= N_EDGES) return;
    float4 r    = rec[(size_t)i * 4 + SLOT];
    float4 meta = rec[(size_t)i * 4 + 2];
    int s = __float_as_int(meta.y);
    int d = __float_as_int(meta.z);
    float4 sa = *reinterpret_cast<const float4*>(al_src + (size_t)s * 4);
    float4 da = *reinterpret_cast<const float4*>(al_dst + (size_t)d * 4);
    float4 wv;
    float al;
    al = sa.x + da.x + r.x; al = (al >= 0.f) ? al : 0.2f * al; wv.x = __expf(al);
    al = sa.y + da.y + r.y; al = (al >= 0.f) ? al : 0.2f * al; wv.y = __expf(al);
    al = sa.z + da.z + r.z; al = (al >= 0.f) ? al : 0.2f * al; wv.z = __expf(al);
    al = sa.w + da.w + r.w; al = (al >= 0.f) ? al : 0.2f * al; wv.w = __expf(al);
    w_csr[i] = wv;
    if (SLOT == 0) src_out[i] = s;
}

__global__ void k_edge_w1(const float4* __restrict__ rec, const float* __restrict__ al_src,
                          const float* __restrict__ al_dst, float* __restrict__ w_csr) {
    int i = blockIdx.x * blockDim.x + threadIdx.x;
    if (i >= N_EDGES) return;
    float4 meta = rec[(size_t)i * 4 + 2];
    int s = __float_as_int(meta.y);
    int d = __float_as_int(meta.z);
    float al = al_src[s] + al_dst[d] + meta.x;
    al = (al >= 0.f) ? al : 0.2f * al;
    w_csr[i] = __expf(al);
}

// ---------------- fused gather: 8 edges/wave in flight, fp16 xp ----------------
template <int H>
__global__ void k_node_agg(const int* __restrict__ offs, const int* __restrict__ src_csr,
                           const float* __restrict__ w_csr, const __half* __restrict__ xp,
                           const float* __restrict__ bias, const float* __restrict__ g,
                           const float* __restrict__ be, const float* __restrict__ hin,
                           float* __restrict__ hout) {
    const int C = HID / H;
    int tid = threadIdx.x;
    int wave = tid >> 6;
    int lane = tid & 63;
    int n = blockIdx.x * 4 + wave;
    if (n >= N_NODES) return;
    int e0 = offs[n], e1 = offs[n + 1];
    int side = lane >> 5;
    int hl = lane & 31;
    int c = hl * 4;
    const int h = c / C;
    float ax = 0.f, ay = 0.f, az = 0.f, aw = 0.f, den = 0.f;

    auto ld = [&](int idx, int& s, float& w) {
        if (idx < e1) {
            s = src_csr[idx];
            w = (H == 4) ? w_csr[(size_t)idx * 4 + h] : w_csr[idx];
        } else { s = 0; w = 0.f; }
    };
    auto acc1 = [&](uint2 r, float w) {
        union { uint2 u; __half2 h2[2]; } t; t.u = r;
        float2 lo = __half22float2(t.h2[0]), hi = __half22float2(t.h2[1]);
        ax += w * lo.x; ay += w * lo.y; az += w * hi.x; aw += w * hi.y; den += w;
    };

    int i = e0 + side;
    int sA, sB, sC, sD; float wA, wB, wC, wD;
    ld(i, sA, wA); ld(i + 2, sB, wB); ld(i + 4, sC, wC); ld(i + 6, sD, wD);
    while (i < e1) {
        uint2 rA = *reinterpret_cast<const uint2*>(xp + (size_t)sA * HID + c);
        uint2 rB = *reinterpret_cast<const uint2*>(xp + (size_t)sB * HID + c);
        uint2 rC = *reinterpret_cast<const uint2*>(xp + (size_t)sC * HID + c);
        uint2 rD = *reinterpret_cast<const uint2*>(xp + (size_t)sD * HID + c);
        int ni = i + 8;
        int tA, tB, tC, tD; float vA, vB, vC, vD;
        ld(ni, tA, vA); ld(ni + 2, tB, vB); ld(ni + 4, tC, vC); ld(ni + 6, tD, vD);
        acc1(rA, wA); acc1(rB, wB); acc1(rC, wC); acc1(rD, wD);
        sA = tA; wA = vA; sB = tB; wB = vB; sC = tC; wC = vC; sD = tD; wD = vD;
        i = ni;
    }
    ax += __shfl_xor(ax, 32, 64);
    ay += __shfl_xor(ay, 32, 64);
    az += __shfl_xor(az, 32, 64);
    aw += __shfl_xor(aw, 32, 64);
    den += __shfl_xor(den, 32, 64);

    float inv = 1.f / (den + 1e-16f);
    const float4 bv = *reinterpret_cast<const float4*>(bias + c);
    float vx = ax * inv + bv.x, vy = ay * inv + bv.y;
    float vz = az * inv + bv.z, vw = aw * inv + bv.w;
    float s4 = vx + vy + vz + vw;
    #pragma unroll
    for (int o = 16; o > 0; o >>= 1) s4 += __shfl_xor(s4, o, 64);
    float mean = s4 * (1.f / HID);
    float dx = vx - mean, dy = vy - mean, dz = vz - mean, dw = vw - mean;
    float q4 = dx * dx + dy * dy + dz * dz + dw * dw;
    #pragma unroll
    for (int o = 16; o > 0; o >>= 1) q4 += __shfl_xor(q4, o, 64);
    float rstd = rsqrtf(q4 * (1.f / HID) + 1e-5f);
    if (side == 0) {
        const float4 gv  = *reinterpret_cast<const float4*>(g + c);
        const float4 bev = *reinterpret_cast<const float4*>(be + c);
        float yx = dx * rstd * gv.x + bev.x;
        float yy = dy * rstd * gv.y + bev.y;
        float yz = dz * rstd * gv.z + bev.z;
        float yw = dw * rstd * gv.w + bev.w;
        yx = (yx > 0.f) ? yx : (__expf(yx) - 1.f);
        yy = (yy > 0.f) ? yy : (__expf(yy) - 1.f);
        yz = (yz > 0.f) ? yz : (__expf(yz) - 1.f);
        yw = (yw > 0.f) ? yw : (__expf(yw) - 1.f);
        const float4 rv = *reinterpret_cast<const float4*>(hin + (size_t)n * HID + c);
        *reinterpret_cast<float4*>(hout + (size_t)n * HID + c) =
            make_float4(yx + rv.x, yy + rv.y, yz + rv.z, yw + rv.w);
    }
}

// ---------------- gate MLP, tiled 16 nodes/block ----------------
__global__ void k_gate(const float* __restrict__ h, const float* __restrict__ gW1,
                       const float* __restrict__ gb1, const float* __restrict__ gW2,
                       const float* __restrict__ gb2, float* __restrict__ gate) {
    __shared__ float hs[16][HID];
    int tid = threadIdx.x;
    int base = blockIdx.x * 16;
    for (int idx = tid; idx < 16 * HID; idx += 256) {
        int nn = idx >> 7, k = idx & 127;
        hs[nn][k] = h[(size_t)(base + nn) * HID + k];
    }
    __syncthreads();
    int c = tid & 63;
    int wave = tid >> 6;
    float acc[4] = {0.f, 0.f, 0.f, 0.f};
    #pragma unroll 8
    for (int k = 0; k < HID; k++) {
        float wv = gW1[k * 64 + c];
        #pragma unroll
        for (int q = 0; q < 4; q++) acc[q] += hs[wave * 4 + q][k] * wv;
    }
    float b1 = gb1[c], w2 = gW2[c];
    float p[4];
    #pragma unroll
    for (int q = 0; q < 4; q++) p[q] = fmaxf(acc[q] + b1, 0.f) * w2;
    #pragma unroll
    for (int o = 32; o > 0; o >>= 1) {
        #pragma unroll
        for (int q = 0; q < 4; q++) p[q] += __shfl_xor(p[q], o, 64);
    }
    if (c == 0) {
        float b2 = gb2[0];
        #pragma unroll
        for (int q = 0; q < 4; q++) gate[base + wave * 4 + q] = p[q] + b2;
    }
}

__global__ void k_bounds(const int* __restrict__ batch, int* __restrict__ goff) {
    int n = blockIdx.x * blockDim.x + threadIdx.x;
    if (n >= N_NODES) return;
    int cur = batch[n];
    int prev = (n == 0) ? -1 : batch[n - 1];
    for (int g = prev + 1; g <= cur; g++) goff[g] = n;
    if (n == N_NODES - 1) {
        for (int g = cur + 1; g <= NB; g++) goff[g] = N_NODES;
    }
}

__global__ void k_gmaxden(const float* __restrict__ gate, const int* __restrict__ goff,
                          float* __restrict__ gmax, float* __restrict__ gden) {
    int b = blockIdx.x;
    int t = threadIdx.x;
    __shared__ float red[256];
    int s = goff[b], e = goff[b + 1];
    float m = -__builtin_inff();
    for (int n = s + t; n < e; n += 256) m = fmaxf(m, gate[n]);
    red[t] = m;
    __syncthreads();
    for (int o = 128; o > 0; o >>= 1) { if (t < o) red[t] = fmaxf(red[t], red[t + o]); __syncthreads(); }
    m = red[0];
    __syncthreads();
    float d = 0.f;
    for (int n = s + t; n < e; n += 256) d += __expf(gate[n] - m);
    red[t] = d;
    __syncthreads();
    for (int o = 128; o > 0; o >>= 1) { if (t < o) red[t] += red[t + o]; __syncthreads(); }
    if (t == 0) { gmax[b] = m; gden[b] = red[0]; }
}

__global__ void k_pool(const float* __restrict__ h, const float* __restrict__ gate,
                       const float* __restrict__ gmax, const float* __restrict__ gden,
                       const int* __restrict__ goff, float* __restrict__ pooled) {
    int b = blockIdx.x;
    int part = blockIdx.y;
    int c = threadIdx.x;
    int s = goff[b], e = goff[b + 1];
    float m = gmax[b];
    float dinv = 1.f / (gden[b] + 1e-16f);
    float acc = 0.f;
    for (int n = s + part; n < e; n += POOL_SPLIT) {
        float att = __expf(gate[n] - m) * dinv;
        acc += att * h[(size_t)n * HID + c];
    }
    atomicAdd(&pooled[b * HID + c], acc);
}

__global__ void k_head(const float* __restrict__ pooled, const float* __restrict__ cW1,
                       const float* __restrict__ cb1, const float* __restrict__ cW2,
                       const float* __restrict__ cb2, float* __restrict__ out) {
    int b = blockIdx.x;
    int t = threadIdx.x;
    __shared__ float pr[HID];
    __shared__ float tr[64];
    pr[t] = pooled[b * HID + t];
    pr[t + 64] = pooled[b * HID + t + 64];
    __syncthreads();
    float a = cb1[t];
    #pragma unroll 8
    for (int k = 0; k < HID; k++) a += pr[k] * cW1[k * 64 + t];
    tr[t] = fmaxf(a, 0.f);
    __syncthreads();
    if (t < NC) {
        float o = cb2[t];
        #pragma unroll
        for (int k = 0; k < 64; k++) o += tr[k] * cW2[k * NC + t];
        out[b * NC + t] = o;
    }
}

extern "C" void kernel_launch(void* const* d_in, const int* in_sizes, int n_in,
                              void* d_out, int out_size, void* d_ws, size_t ws_size,
                              hipStream_t stream) {
    (void)in_sizes; (void)n_in; (void)out_size; (void)ws_size;
    const float* x     = (const float*)d_in[0];
    const int*   ei    = (const int*)d_in[1];
    const float* ea    = (const float*)d_in[2];
    const int*   batch = (const int*)d_in[3];
    const float* pW    = (const float*)d_in[4];
    const float* pb    = (const float*)d_in[5];
    const float *W[3], *as_[3], *ad_[3], *ae_[3], *We[3], *bb[3], *gg[3], *be[3];
    for (int l = 0; l < 3; l++) {
        int base = 6 + 8 * l;
        W[l]   = (const float*)d_in[base + 0];
        as_[l] = (const float*)d_in[base + 1];
        ad_[l] = (const float*)d_in[base + 2];
        ae_[l] = (const float*)d_in[base + 3];
        We[l]  = (const float*)d_in[base + 4];
        bb[l]  = (const float*)d_in[base + 5];
        gg[l]  = (const float*)d_in[base + 6];
        be[l]  = (const float*)d_in[base + 7];
    }
    const float* gW1 = (const float*)d_in[30];
    const float* gb1 = (const float*)d_in[31];
    const float* gW2 = (const float*)d_in[32];
    const float* gb2 = (const float*)d_in[33];
    const float* cW1 = (const float*)d_in[34];
    const float* cb1 = (const float*)d_in[35];
    const float* cW2 = (const float*)d_in[36];
    const float* cb2 = (const float*)d_in[37];
    float* out = (float*)d_out;

    char* p = (char*)d_ws;
    auto take = [&](size_t bytes) -> char* {
        char* r = p;
        p += (bytes + 255) & ~(size_t)255;
        return r;
    };
    float*  h0      = (float*)take((size_t)N_NODES * HID * 4);
    float*  h1      = (float*)take((size_t)N_NODES * HID * 4);
    __half* xp      = (__half*)take((size_t)N_NODES * HID * 2);
    float*  al_src  = (float*)take((size_t)N_NODES * 4 * 4);
    float*  al_dst  = (float*)take((size_t)N_NODES * 4 * 4);
    float*  w_csr   = (float*)take((size_t)N_EDGES * 4 * 4);
    float4* rec     = (float4*)take((size_t)N_EDGES * 64);
    int*    deg     = (int*)take((size_t)N_NODES * 4);
    int*    offs    = (int*)take((size_t)(N_NODES + 1) * 4);
    int*    rank    = (int*)take((size_t)N_EDGES * 4);
    int*    src_csr = (int*)take((size_t)N_EDGES * 4);
    int*    bsum    = (int*)take(256 * 4);
    int*    bpre    = (int*)take(256 * 4);
    float*  WeAe    = (float*)take(ED * 9 * 4);
    float*  gate    = (float*)take((size_t)N_NODES * 4);
    float*  gmax    = (float*)take(NB * 4);
    float*  gden    = (float*)take(NB * 4);
    int*    goff    = (int*)take((NB + 1) * 4);
    float*  pooled  = (float*)take(NB * HID * 4);
    f16*    Wtp     = (f16*)take(128 * 64 * 2);
    f16*    Wt0     = (f16*)take(128 * 128 * 2);
    f16*    Wt1     = (f16*)take(128 * 128 * 2);
    f16*    Wt2     = (f16*)take(128 * 128 * 2);
    f16*    Wt[3]   = {Wt0, Wt1, Wt2};

    const int* src = ei;
    const int* dst = ei + N_EDGES;

    hipMemsetAsync(deg, 0, (size_t)N_NODES * 4, stream);
    hipMemsetAsync(pooled, 0, (size_t)NB * HID * 4, stream);

    k_wcvt<<<64, 256, 0, stream>>>(pW, W[0], W[1], W[2], Wtp, Wt0, Wt1, Wt2);
    k_gemm<64, 0><<<GEMM_BLOCKS, 256, 0, stream>>>(x, Wtp, pb, nullptr, nullptr,
                                                   h0, nullptr, nullptr, nullptr);
    k_deg<<<(N_EDGES + 255) / 256, 256, 0, stream>>>(dst, deg, rank);
    k_scanA<<<SCAN_BLOCKS, 256, 0, stream>>>(deg, bsum);
    k_scanB<<<1, 256, 0, stream>>>(bsum, bpre, offs);
    k_scanC<<<SCAN_BLOCKS, 256, 0, stream>>>(deg, bpre, offs);
    k_weae_all<<<1, 256, 0, stream>>>(We[0], ae_[0], We[1], ae_[1], We[2], ae_[2], WeAe);
    k_edge_build<<<(N_EDGES + 255) / 256, 256, 0, stream>>>(src, dst, rank, offs, ea, WeAe, rec);

    float* hc = h0;
    float* hn = h1;
    for (int l = 0; l < 3; l++) {
        if (l < 2) {
            k_gemm<128, 1><<<GEMM_BLOCKS, 256, 0, stream>>>(hc, Wt[l], nullptr, as_[l], ad_[l],
                                                            nullptr, xp, al_src, al_dst);
            if (l == 0)
                k_edge_w4<0><<<(N_EDGES + 255) / 256, 256, 0, stream>>>(rec, al_src, al_dst,
                                                                        (float4*)w_csr, src_csr);
            else
                k_edge_w4<1><<<(N_EDGES + 255) / 256, 256, 0, stream>>>(rec, al_src, al_dst,
                                                                        (float4*)w_csr, nullptr);
            k_node_agg<4><<<(N_NODES + 3) / 4, 256, 0, stream>>>(offs, src_csr, w_csr, xp,
                                                                 bb[l], gg[l], be[l], hc, hn);
        } else {
            k_gemm<128, 2><<<GEMM_BLOCKS, 256, 0, stream>>>(hc, Wt[l], nullptr, as_[l], ad_[l],
                                                            nullptr, xp, al_src, al_dst);
            k_edge_w1<<<(N_EDGES + 255) / 256, 256, 0, stream>>>(rec, al_src, al_dst, w_csr);
            k_node_agg<1><<<(N_NODES + 3) / 4, 256, 0, stream>>>(offs, src_csr, w_csr, xp,
                                                                 bb[l], gg[l], be[l], hc, hn);
        }
        float* t = hc; hc = hn; hn = t;
    }

    k_gate<<<N_NODES / 16, 256, 0, stream>>>(hc, gW1, gb1, gW2, gb2, gate);
    k_bounds<<<(N_NODES + 255) / 256, 256, 0, stream>>>(batch, goff);
    k_gmaxden<<<NB, 256, 0, stream>>>(gate, goff, gmax, gden);
    k_pool<<<dim3(NB, POOL_SPLIT), HID, 0, stream>>>(hc, gate, gmax, gden, goff, pooled);
    k_head<<<NB, 64, 0, stream>>>(pooled, cW1, cb1, cW2, cb2, out);
}